// Round 2
// baseline (3464.096 us; speedup 1.0000x reference)
//
#include <hip/hip_runtime.h>

#define BATCH 32
#define SEQ   512
#define DM    512
#define NL    4
#define DSTATE 64
#define DCONV 4
#define DI    1024   // D_INNER
#define NH    16
#define HD    64
#define PREDN 96
#define CDIM  1152   // DI + 2*DSTATE
#define DPROJ 2192   // 2*DI + 2*DSTATE + NH
#define EPSF  1e-5f

typedef float  f32x4  __attribute__((ext_vector_type(4)));
typedef __bf16 bf16x8 __attribute__((ext_vector_type(8)));

template<class X,class Y> struct same_t { static constexpr bool v=false; };
template<class X> struct same_t<X,X>    { static constexpr bool v=true;  };

__device__ __forceinline__ float sigmoidf_(float x){ return 1.f/(1.f+__expf(-x)); }
__device__ __forceinline__ float siluf_(float x){ return x*sigmoidf_(x); }
__device__ __forceinline__ float softplusf_(float x){ return (x>20.f)?x:log1pf(__expf(x)); }

// ---------------------------------------------------------------------------
// GEMM (B-transposed): C[M,N] = A[M,K] * Bw[N,K]^T (+bias).
// A: bf16 activations. Bw: fp32 weights (converted to bf16 in staging).
// C: bf16 or fp32 (template). Tile 64x64, BK=64, 4 waves of 2x2 MFMA tiles.
// LDS row stride 88 elems (176 B = 16B-aligned rows, <=2-way bank alias=free).
// Layouts (verified): A/B frag row = lane&15, k = (lane>>4)*8 + j
//                     C/D frag col = lane&15, row = (lane>>4)*4 + reg
// ---------------------------------------------------------------------------
#define LDT 88
template<typename TC>
__global__ __launch_bounds__(256) void gemm_bt64(
    const __bf16* __restrict__ A, const float* __restrict__ Bw,
    TC* __restrict__ C, const float* __restrict__ bias,
    int M, int N, int K)
{
  __shared__ __bf16 As[64*LDT];
  __shared__ __bf16 Bs[64*LDT];
  const int tid  = threadIdx.x;
  const int m0   = blockIdx.y*64, n0 = blockIdx.x*64;
  const int wave = tid>>6, lane = tid&63;
  const int wm   = (wave>>1)*32, wn = (wave&1)*32;
  const int l15  = lane&15, quad = lane>>4;
  const int sr   = tid>>2, sc = (tid&3)*16;   // staging: row, 16-col segment

  f32x4 acc00={0,0,0,0}, acc01={0,0,0,0}, acc10={0,0,0,0}, acc11={0,0,0,0};

  for (int k0=0; k0<K; k0+=64){
    // ---- stage A tile (bf16 source, straight copy) ----
    {
      bf16x8 p0, p1;
      #pragma unroll
      for (int i=0;i<8;++i){ p0[i]=(__bf16)0.f; p1[i]=(__bf16)0.f; }
      const int r = m0+sr;
      if (r < M){
        const bf16x8* s = (const bf16x8*)(A + (size_t)r*K + k0 + sc);
        p0 = s[0]; p1 = s[1];
      }
      *(bf16x8*)&As[sr*LDT+sc]   = p0;
      *(bf16x8*)&As[sr*LDT+sc+8] = p1;
    }
    // ---- stage B tile (fp32 weights -> bf16) ----
    {
      float4 v0={0,0,0,0}, v1=v0, v2=v0, v3=v0;
      const int r = n0+sr;
      if (r < N){
        const float4* s4 = (const float4*)(Bw + (size_t)r*K + k0 + sc);
        v0=s4[0]; v1=s4[1]; v2=s4[2]; v3=s4[3];
      }
      bf16x8 p0,p1;
      p0[0]=(__bf16)v0.x; p0[1]=(__bf16)v0.y; p0[2]=(__bf16)v0.z; p0[3]=(__bf16)v0.w;
      p0[4]=(__bf16)v1.x; p0[5]=(__bf16)v1.y; p0[6]=(__bf16)v1.z; p0[7]=(__bf16)v1.w;
      p1[0]=(__bf16)v2.x; p1[1]=(__bf16)v2.y; p1[2]=(__bf16)v2.z; p1[3]=(__bf16)v2.w;
      p1[4]=(__bf16)v3.x; p1[5]=(__bf16)v3.y; p1[6]=(__bf16)v3.z; p1[7]=(__bf16)v3.w;
      *(bf16x8*)&Bs[sr*LDT+sc]   = p0;
      *(bf16x8*)&Bs[sr*LDT+sc+8] = p1;
    }
    __syncthreads();
    #pragma unroll
    for (int ks=0; ks<64; ks+=32){
      const int kf = ks + quad*8;
      bf16x8 a0 = *(const bf16x8*)&As[(wm     +l15)*LDT+kf];
      bf16x8 a1 = *(const bf16x8*)&As[(wm+16  +l15)*LDT+kf];
      bf16x8 b0 = *(const bf16x8*)&Bs[(wn     +l15)*LDT+kf];
      bf16x8 b1 = *(const bf16x8*)&Bs[(wn+16  +l15)*LDT+kf];
      acc00 = __builtin_amdgcn_mfma_f32_16x16x32_bf16(a0,b0,acc00,0,0,0);
      acc01 = __builtin_amdgcn_mfma_f32_16x16x32_bf16(a0,b1,acc01,0,0,0);
      acc10 = __builtin_amdgcn_mfma_f32_16x16x32_bf16(a1,b0,acc10,0,0,0);
      acc11 = __builtin_amdgcn_mfma_f32_16x16x32_bf16(a1,b1,acc11,0,0,0);
    }
    __syncthreads();
  }

  // ---- epilogue ----
  {
    const f32x4 accs[4] = {acc00, acc01, acc10, acc11};
    #pragma unroll
    for (int mi=0; mi<2; ++mi){
      #pragma unroll
      for (int ni=0; ni<2; ++ni){
        f32x4 a = accs[mi*2+ni];
        int col = n0 + wn + ni*16 + l15;
        if (col < N){
          float badd = bias ? bias[col] : 0.f;
          #pragma unroll
          for (int r=0; r<4; ++r){
            int row = m0 + wm + mi*16 + quad*4 + r;
            if (row < M) C[(size_t)row*N + col] = (TC)(a[r] + badd);
          }
        }
      }
    }
  }
}

// ---------------------------------------------------------------------------
__global__ __launch_bounds__(256) void cast_bf16_k(
    const float* __restrict__ src, __bf16* __restrict__ dst, int n)
{
  int i = blockIdx.x*256 + threadIdx.x;
  if (i < n) dst[i] = (__bf16)src[i];
}

// ---------------------------------------------------------------------------
// Causal depthwise conv (width 4) + bias + SiLU over the xBC slice of zxbcdt.
// ---------------------------------------------------------------------------
__global__ __launch_bounds__(256) void conv_silu_k(
    const __bf16* __restrict__ zx, const float* __restrict__ cw,
    const float* __restrict__ cb, __bf16* __restrict__ out)
{
  int idx = blockIdx.x*256 + threadIdx.x;
  if (idx >= BATCH*SEQ*CDIM) return;
  int d  = idx % CDIM;
  int bt = idx / CDIM;
  int t  = bt % SEQ;
  int b  = bt / SEQ;
  const __bf16* src = zx + (size_t)b*SEQ*DPROJ + DI + d;
  float w0=cw[d*4+0], w1=cw[d*4+1], w2=cw[d*4+2], w3=cw[d*4+3];
  float acc = cb[d];
  if (t>=3) acc += (float)src[(size_t)(t-3)*DPROJ]*w0;
  if (t>=2) acc += (float)src[(size_t)(t-2)*DPROJ]*w1;
  if (t>=1) acc += (float)src[(size_t)(t-1)*DPROJ]*w2;
  acc += (float)src[(size_t)t*DPROJ]*w3;
  out[idx] = (__bf16)siluf_(acc);
}

// ---------------------------------------------------------------------------
// SSD scan. One 64-lane wave per (b, head). Lane p holds h[p][0..63] (fp32).
// ---------------------------------------------------------------------------
__global__ __launch_bounds__(64) void ssd_scan_k(
    const __bf16* __restrict__ xc,   // (B,SEQ,CDIM) conv output
    const __bf16* __restrict__ zx,   // (B,SEQ,DPROJ) raw dt tail
    const float* __restrict__ dtb_, const float* __restrict__ alog_,
    const float* __restrict__ dp_,  __bf16* __restrict__ y)
{
  const int bh = blockIdx.x;
  const int b = bh >> 4, h = bh & 15;
  const int p = threadIdx.x;
  const float Ah  = -__expf(alog_[h]);
  const float dtb = dtb_[h];
  const float Dh  = dp_[h];
  float hs[DSTATE];
  #pragma unroll
  for (int n=0;n<DSTATE;++n) hs[n]=0.f;

  const __bf16* xbase  = xc + (size_t)b*SEQ*CDIM;
  const __bf16* dtbase = zx + (size_t)b*SEQ*DPROJ + (DPROJ-NH) + h;
  __bf16*       ybase  = y  + (size_t)b*SEQ*DI + h*HD + p;

  float dtr = (float)dtbase[0];
  float xv  = (float)xbase[h*HD + p];
  for (int t=0; t<SEQ; ++t){
    const __bf16* xrow = xbase + (size_t)t*CDIM;
    float dtr_c = dtr, xv_c = xv;
    if (t+1 < SEQ){                      // prefetch next step's inputs
      dtr = (float)dtbase[(size_t)(t+1)*DPROJ];
      xv  = (float)xrow[CDIM + h*HD + p];
    }
    float dt = softplusf_(dtr_c + dtb);
    float dA = __expf(dt*Ah);
    float cc = dt*xv_c;
    const bf16x8* Bv = (const bf16x8*)(xrow + DI);
    const bf16x8* Cv = (const bf16x8*)(xrow + DI + DSTATE);
    float acc = 0.f;
    #pragma unroll
    for (int j=0;j<8;++j){
      bf16x8 bb = Bv[j];
      bf16x8 cv = Cv[j];
      #pragma unroll
      for (int e=0;e<8;++e){
        int n = j*8+e;
        float hn = hs[n]*dA + cc*(float)bb[e];
        hs[n] = hn;
        acc += hn*(float)cv[e];
      }
    }
    ybase[(size_t)t*DI] = (__bf16)(acc + xv_c*Dh);
  }
}

// ---------------------------------------------------------------------------
// y = y*silu(z); y *= rsqrt(mean(y^2)+eps)*norm_w   (in-place, bf16 IO)
// ---------------------------------------------------------------------------
__global__ __launch_bounds__(256) void gate_rms_k(
    __bf16* __restrict__ y, const __bf16* __restrict__ zx, const float* __restrict__ nw)
{
  __shared__ float red[4];
  const int row = blockIdx.x;
  __bf16* yrow = y + (size_t)row*DI;
  const __bf16* zrow = zx + (size_t)row*DPROJ;   // z = first DI cols
  const int tid = threadIdx.x;
  float u[4]; float ss = 0.f;
  #pragma unroll
  for (int j=0;j<4;++j){
    int i = tid + j*256;
    float uu = (float)yrow[i]*siluf_((float)zrow[i]);
    u[j] = uu; ss += uu*uu;
  }
  #pragma unroll
  for (int o=32;o;o>>=1) ss += __shfl_xor(ss,o);
  if ((tid&63)==0) red[tid>>6] = ss;
  __syncthreads();
  ss = red[0]+red[1]+red[2]+red[3];
  const float sc = rsqrtf(ss*(1.f/DI) + EPSF);
  #pragma unroll
  for (int j=0;j<4;++j){
    int i = tid + j*256;
    yrow[i] = (__bf16)(u[j]*sc*nw[i]);
  }
}

// ---------------------------------------------------------------------------
// xcur = layernorm(tmp + xcur)*w + b   (in-place on xcur; one block per row)
// Safe in-place: each thread reads its own 2 elems before any write.
// ---------------------------------------------------------------------------
__global__ __launch_bounds__(256) void add_ln_k(
    const __bf16* __restrict__ tmp, __bf16* __restrict__ resio,
    const float* __restrict__ w, const float* __restrict__ bb)
{
  __shared__ float red[4];
  const int row = blockIdx.x;
  const int tid = threadIdx.x;
  const __bf16* trow = tmp + (size_t)row*DM;
  __bf16* rrow = resio + (size_t)row*DM;
  float v0 = (float)trow[tid]     + (float)rrow[tid];
  float v1 = (float)trow[tid+256] + (float)rrow[tid+256];
  float s = v0+v1;
  #pragma unroll
  for (int o=32;o;o>>=1) s += __shfl_xor(s,o);
  if ((tid&63)==0) red[tid>>6] = s;
  __syncthreads();
  s = red[0]+red[1]+red[2]+red[3];
  const float mean = s*(1.f/DM);
  float d0=v0-mean, d1=v1-mean;
  float q = d0*d0 + d1*d1;
  #pragma unroll
  for (int o=32;o;o>>=1) q += __shfl_xor(q,o);
  __syncthreads();
  if ((tid&63)==0) red[tid>>6] = q;
  __syncthreads();
  q = red[0]+red[1]+red[2]+red[3];
  const float rstd = rsqrtf(q*(1.f/DM) + EPSF);
  rrow[tid]     = (__bf16)(d0*rstd*w[tid]     + bb[tid]);
  rrow[tid+256] = (__bf16)(d1*rstd*w[tid+256] + bb[tid+256]);
}

// ---------------------------------------------------------------------------
// gather last PREDN timesteps: (B,PREDN,DM) <- xcur[b, SEQ-PREDN+t, :]
// ---------------------------------------------------------------------------
__global__ __launch_bounds__(256) void gather_k(
    const __bf16* __restrict__ xc, __bf16* __restrict__ g)
{
  int idx = blockIdx.x*256 + threadIdx.x;
  if (idx >= BATCH*PREDN*DM) return;
  int dcol = idx & (DM-1);
  int r = idx >> 9;                         // DM = 512
  int b = r / PREDN, t = (SEQ-PREDN) + (r % PREDN);
  g[idx] = xc[((size_t)b*SEQ + t)*DM + dcol];
}

// ---------------------------------------------------------------------------
extern "C" void kernel_launch(void* const* d_in, const int* in_sizes, int n_in,
                              void* d_out, int out_size, void* d_ws, size_t ws_size,
                              hipStream_t stream)
{
  const float* x         = (const float*)d_in[0];
  const float* in_proj_w = (const float*)d_in[1];
  const float* conv_w    = (const float*)d_in[2];
  const float* conv_b    = (const float*)d_in[3];
  const float* dt_bias   = (const float*)d_in[4];
  const float* A_log     = (const float*)d_in[5];
  const float* Dp        = (const float*)d_in[6];
  const float* norm_w    = (const float*)d_in[7];
  const float* out_proj_w= (const float*)d_in[8];
  const float* ln_w      = (const float*)d_in[9];
  const float* ln_b      = (const float*)d_in[10];
  const float* final_w   = (const float*)d_in[11];
  const float* final_b   = (const float*)d_in[12];
  float* out = (float*)d_out;

  const size_t ROWS = (size_t)BATCH*SEQ;        // 16384
  // bf16 workspace layout (~160 MB total)
  __bf16* zx   = (__bf16*)d_ws;                 // ROWS*DPROJ   71.8 MB
  __bf16* xBCc = zx   + ROWS*DPROJ;             // ROWS*CDIM    37.7 MB
  __bf16* ybuf = xBCc + ROWS*CDIM;              // ROWS*DI      33.6 MB
  __bf16* xcur = ybuf + ROWS*DI;                // ROWS*DM      16.8 MB
  __bf16* tmp  = xBCc;                          // reuse (free after scan)
  __bf16* gbuf = ybuf;                          // reuse (free after layers)

  const int convTotal = BATCH*SEQ*CDIM;
  const int nX = (int)(ROWS*DM);

  // cast input to bf16 residual stream
  cast_bf16_k<<<(nX+255)/256, 256, 0, stream>>>(x, xcur, nX);

  for (int l=0; l<NL; ++l){
    // 1) in_proj: zx = xcur @ W_in^T   (M=16384, N=2192, K=512)
    gemm_bt64<__bf16><<<dim3((DPROJ+63)/64, (int)(ROWS/64)), 256, 0, stream>>>(
        xcur, in_proj_w + (size_t)l*DPROJ*DM, zx, nullptr, (int)ROWS, DPROJ, DM);
    // 2) causal dwconv + silu
    conv_silu_k<<<(convTotal+255)/256, 256, 0, stream>>>(
        zx, conv_w + (size_t)l*CDIM*DCONV, conv_b + (size_t)l*CDIM, xBCc);
    // 3) SSD scan
    ssd_scan_k<<<BATCH*NH, 64, 0, stream>>>(
        xBCc, zx, dt_bias + l*NH, A_log + l*NH, Dp + l*NH, ybuf);
    // 4) gate + rmsnorm (in place on ybuf)
    gate_rms_k<<<(int)ROWS, 256, 0, stream>>>(ybuf, zx, norm_w + (size_t)l*DI);
    // 5) out_proj: tmp = ybuf @ W_out^T  (M=16384, N=512, K=1024)
    gemm_bt64<__bf16><<<dim3(DM/64, (int)(ROWS/64)), 256, 0, stream>>>(
        ybuf, out_proj_w + (size_t)l*DM*DI, tmp, nullptr, (int)ROWS, DM, DI);
    // 6) residual + layernorm, in place on xcur
    add_ln_k<<<(int)ROWS, 256, 0, stream>>>(tmp, xcur, ln_w + l*DM, ln_b + l*DM);
  }
  // 7) slice last PREDN steps
  gather_k<<<(BATCH*PREDN*DM+255)/256, 256, 0, stream>>>(xcur, gbuf);
  // 8) final head: out = gbuf @ final_w^T + final_b  (M=3072, N=512, K=512)
  gemm_bt64<float><<<dim3(DM/64, (BATCH*PREDN)/64), 256, 0, stream>>>(
      gbuf, final_w, out, final_b, BATCH*PREDN, DM, DM);
}

// Round 4
// 1253.568 us; speedup vs baseline: 2.7634x; 2.7634x over previous
//
#include <hip/hip_runtime.h>
#include <stdint.h>

#define BATCH 32
#define SEQ   512
#define DM    512
#define NL    4
#define DSTATE 64
#define DI    1024   // D_INNER
#define NH    16
#define HD    64
#define PREDN 96
#define CDIM  1152   // DI + 2*DSTATE
#define DPROJ 2192
#define XBW   1168   // xBC (1152) + dt (16) columns
#define NC    8      // chunks per sequence
#define EPSF  1e-5f

typedef float  f32x4  __attribute__((ext_vector_type(4)));
typedef __bf16 bf16x8 __attribute__((ext_vector_type(8)));

__device__ __forceinline__ float sigmoidf_(float x){ return 1.f/(1.f+__expf(-x)); }
__device__ __forceinline__ float siluf_(float x){ return x*sigmoidf_(x); }
__device__ __forceinline__ float softplusf_(float x){ return (x>20.f)?x:log1pf(__expf(x)); }

// direct global->LDS async copy, 16B per lane
__device__ __forceinline__ void gld16(const void* g, void* l){
  __builtin_amdgcn_global_load_lds((__attribute__((address_space(1))) void*)g,
                                   (__attribute__((address_space(3))) void*)l, 16, 0, 0);
}

// ---------------------------------------------------------------------------
// GEMM (B-transposed): C[M,N] = A[M,K] * W[N,K]^T (+bias). bf16 in, MFMA,
// 128x128 tile, BK=64, global_load_lds staging (m97 structure).
// ---------------------------------------------------------------------------
template<typename TC>
__global__ __launch_bounds__(256) void gemm128(
    const __bf16* __restrict__ A, const __bf16* __restrict__ W,
    TC* __restrict__ C, const float* __restrict__ bias,
    int M, int Nreal, int ldc, int K)
{
  __shared__ __bf16 sA[128*64];
  __shared__ __bf16 sW[128*64];
  const int tid  = threadIdx.x;
  const int m0   = blockIdx.y*128, n0 = blockIdx.x*128;
  const int lane = tid&63, wave = tid>>6;
  const int l15  = lane&15, quad = lane>>4;
  const int wr   = (wave>>1)*64, wc = (wave&1)*64;
  f32x4 acc[4][4];
  #pragma unroll
  for (int a=0;a<4;++a)
    #pragma unroll
    for (int b=0;b<4;++b) acc[a][b] = (f32x4){0,0,0,0};

  for (int k0=0; k0<K; k0+=64){
    #pragma unroll
    for (int j=0;j<4;++j){
      const int f = j*256 + tid;
      const int r = f>>3, kc = (f&7)*8;
      gld16(A + (size_t)(m0+r)*K + k0 + kc, &sA[f*8]);
      int rb = n0 + r; rb = rb < Nreal ? rb : (Nreal-1);
      gld16(W + (size_t)rb*K + k0 + kc, &sW[f*8]);
    }
    __syncthreads();
    #pragma unroll
    for (int kk=0; kk<64; kk+=32){
      const int kf = kk + quad*8;
      bf16x8 av[4], bv[4];
      #pragma unroll
      for (int mi=0;mi<4;++mi) av[mi] = *(const bf16x8*)&sA[(wr+mi*16+l15)*64+kf];
      #pragma unroll
      for (int ni=0;ni<4;++ni) bv[ni] = *(const bf16x8*)&sW[(wc+ni*16+l15)*64+kf];
      #pragma unroll
      for (int mi=0;mi<4;++mi)
        #pragma unroll
        for (int ni=0;ni<4;++ni)
          acc[mi][ni] = __builtin_amdgcn_mfma_f32_16x16x32_bf16(av[mi],bv[ni],acc[mi][ni],0,0,0);
    }
    __syncthreads();
  }
  #pragma unroll
  for (int ni=0;ni<4;++ni){
    const int col = n0 + wc + ni*16 + l15;
    if (col < Nreal){
      const float badd = bias ? bias[col] : 0.f;
      #pragma unroll
      for (int mi=0;mi<4;++mi){
        #pragma unroll
        for (int r4=0;r4<4;++r4){
          const int row = m0 + wr + mi*16 + quad*4 + r4;
          C[(size_t)row*ldc + col] = (TC)(acc[mi][ni][r4] + badd);
        }
      }
    }
  }
}

// ---------------------------------------------------------------------------
__global__ __launch_bounds__(256) void cast_bf16_k(
    const float* __restrict__ src, __bf16* __restrict__ dst, int n)
{
  int i = blockIdx.x*256 + threadIdx.x;
  if (i < n) dst[i] = (__bf16)src[i];
}

// ---------------------------------------------------------------------------
// Causal depthwise conv (width 4) + bias + SiLU.
// ---------------------------------------------------------------------------
__global__ __launch_bounds__(256) void conv_silu_k(
    const __bf16* __restrict__ xbw, const float* __restrict__ cw,
    const float* __restrict__ cb, __bf16* __restrict__ xout,
    __bf16* __restrict__ bcout)
{
  int idx = blockIdx.x*256 + threadIdx.x;
  if (idx >= BATCH*SEQ*CDIM) return;
  int d  = idx % CDIM;
  int bt = idx / CDIM;
  int t  = bt % SEQ;
  int b  = bt / SEQ;
  const __bf16* src = xbw + (size_t)b*SEQ*XBW + d;
  float w0=cw[d*4+0], w1=cw[d*4+1], w2=cw[d*4+2], w3=cw[d*4+3];
  float acc = cb[d];
  if (t>=3) acc += (float)src[(size_t)(t-3)*XBW]*w0;
  if (t>=2) acc += (float)src[(size_t)(t-2)*XBW]*w1;
  if (t>=1) acc += (float)src[(size_t)(t-1)*XBW]*w2;
  acc += (float)src[(size_t)t*XBW]*w3;
  float v = siluf_(acc);
  if (d < DI) xout [((size_t)b*SEQ + t)*DI  + d]        = (__bf16)v;
  else        bcout[((size_t)b*SEQ + t)*128 + (d-DI)]   = (__bf16)v;
}

// ---------------------------------------------------------------------------
// dt = softplus(raw+bias); cs = within-chunk inclusive cumsum of dt*A.
// ---------------------------------------------------------------------------
__global__ __launch_bounds__(64) void dtcs_k(
    const __bf16* __restrict__ xbw, const float* __restrict__ dtb_,
    const float* __restrict__ alog_, float* __restrict__ g_dt,
    float* __restrict__ g_cs)
{
  const int bid = blockIdx.x;
  const int c = bid & 7, h = (bid>>3)&15, b = bid>>7;
  const int j = threadIdx.x, t = c*64 + j;
  float raw = (float)xbw[((size_t)b*SEQ + t)*XBW + CDIM + h];
  float dt  = softplusf_(raw + dtb_[h]);
  float s   = dt * (-__expf(alog_[h]));
  #pragma unroll
  for (int off=1; off<64; off<<=1){
    float v = __shfl_up(s, off);
    if (j >= off) s += v;
  }
  const size_t o = ((size_t)b*NH + h)*SEQ + t;
  g_dt[o] = dt; g_cs[o] = s;
}

// ---------------------------------------------------------------------------
// SSD intra-chunk. Decay applied as exp(cs_i - cs_j) computed DIRECTLY on the
// difference (<=0 for used entries) -- the factored exp(cs_i)*exp(-cs_j) form
// overflows (cs reaches -100..-400). min-clamp keeps discarded j>i finite.
// ---------------------------------------------------------------------------
__global__ __launch_bounds__(256) void ssd_chunk_k(
    const __bf16* __restrict__ bc, __bf16* __restrict__ xy,
    const float* __restrict__ g_dt, const float* __restrict__ g_cs,
    const float* __restrict__ dp_, __bf16* __restrict__ gHc)
{
  __shared__ __bf16 sB[64*72], sC[64*72], sXT[64*72], sBwT[64*72], sS[64*72];
  __shared__ float sCS[64], sDT[64];
  const int bid = blockIdx.x;
  const int h = bid & 15, c = (bid>>4)&7, b = bid>>7;
  const int tid = threadIdx.x, wave = tid>>6, lane = tid&63;
  const int l15 = lane&15, quad = lane>>4;
  const int wm = (wave>>1)*32, wn = (wave&1)*32;
  const int t0 = c*64;
  const size_t bh = (size_t)b*NH + h;

  if (tid < 64){
    sCS[tid] = g_cs[bh*SEQ + t0 + tid];
    sDT[tid] = g_dt[bh*SEQ + t0 + tid];
  }
  __syncthreads();

  {
    const int r = tid>>2, seg = (tid&3)*16;
    const __bf16* row = bc + ((size_t)b*SEQ + t0 + r)*128;
    bf16x8 vb0 = *(const bf16x8*)(row + seg);
    bf16x8 vb1 = *(const bf16x8*)(row + seg + 8);
    bf16x8 vc0 = *(const bf16x8*)(row + 64 + seg);
    bf16x8 vc1 = *(const bf16x8*)(row + 64 + seg + 8);
    *(bf16x8*)&sB[r*72+seg]   = vb0;
    *(bf16x8*)&sB[r*72+seg+8] = vb1;
    *(bf16x8*)&sC[r*72+seg]   = vc0;
    *(bf16x8*)&sC[r*72+seg+8] = vc1;
    const float w = __expf(sCS[63] - sCS[r]) * sDT[r];   // exponent <= 0
    #pragma unroll
    for (int e=0;e<8;++e){
      sBwT[(seg+e)*72 + r]   = (__bf16)(w*(float)vb0[e]);
      sBwT[(seg+8+e)*72 + r] = (__bf16)(w*(float)vb1[e]);
    }
    const __bf16* xrow = xy + ((size_t)b*SEQ + t0 + r)*DI + h*64;
    bf16x8 vx0 = *(const bf16x8*)(xrow + seg);
    bf16x8 vx1 = *(const bf16x8*)(xrow + seg + 8);
    #pragma unroll
    for (int e=0;e<8;++e){
      sXT[(seg+e)*72 + r]   = vx0[e];
      sXT[(seg+8+e)*72 + r] = vx1[e];
    }
  }
  __syncthreads();

  // mm1: S[i][j] = sum_n C[i,n]*B[j,n]
  f32x4 aS[2][2];
  #pragma unroll
  for (int a=0;a<2;++a)
    #pragma unroll
    for (int d=0;d<2;++d) aS[a][d] = (f32x4){0,0,0,0};
  #pragma unroll
  for (int kk=0; kk<64; kk+=32){
    const int kf = kk + quad*8;
    bf16x8 a0 = *(const bf16x8*)&sC[(wm+l15)*72+kf];
    bf16x8 a1 = *(const bf16x8*)&sC[(wm+16+l15)*72+kf];
    bf16x8 b0 = *(const bf16x8*)&sB[(wn+l15)*72+kf];
    bf16x8 b1 = *(const bf16x8*)&sB[(wn+16+l15)*72+kf];
    aS[0][0] = __builtin_amdgcn_mfma_f32_16x16x32_bf16(a0,b0,aS[0][0],0,0,0);
    aS[0][1] = __builtin_amdgcn_mfma_f32_16x16x32_bf16(a0,b1,aS[0][1],0,0,0);
    aS[1][0] = __builtin_amdgcn_mfma_f32_16x16x32_bf16(a1,b0,aS[1][0],0,0,0);
    aS[1][1] = __builtin_amdgcn_mfma_f32_16x16x32_bf16(a1,b1,aS[1][1],0,0,0);
  }
  // mask + decay (direct-difference exp), write S to LDS
  #pragma unroll
  for (int mi=0;mi<2;++mi)
    #pragma unroll
    for (int ni=0;ni<2;++ni)
      #pragma unroll
      for (int r4=0;r4<4;++r4){
        const int i = wm+mi*16+quad*4+r4, j = wn+ni*16+l15;
        float ed = __expf(fminf(sCS[i]-sCS[j], 0.f)) * sDT[j];
        float v = aS[mi][ni][r4]*ed;
        sS[i*72+j] = (__bf16)((j<=i)? v : 0.f);
      }
  __syncthreads();

  // mm2: Y[i][p] = sum_j S[i,j]*X[j,p];  mm3: H[n][p] = sum_j Bw[j,n]*X[j,p]
  f32x4 aY[2][2], aH[2][2];
  #pragma unroll
  for (int a=0;a<2;++a)
    #pragma unroll
    for (int d=0;d<2;++d){ aY[a][d]=(f32x4){0,0,0,0}; aH[a][d]=(f32x4){0,0,0,0}; }
  #pragma unroll
  for (int kk=0; kk<64; kk+=32){
    const int kf = kk + quad*8;
    bf16x8 b0 = *(const bf16x8*)&sXT[(wn+l15)*72+kf];
    bf16x8 b1 = *(const bf16x8*)&sXT[(wn+16+l15)*72+kf];
    bf16x8 s0 = *(const bf16x8*)&sS[(wm+l15)*72+kf];
    bf16x8 s1 = *(const bf16x8*)&sS[(wm+16+l15)*72+kf];
    bf16x8 w0 = *(const bf16x8*)&sBwT[(wm+l15)*72+kf];
    bf16x8 w1 = *(const bf16x8*)&sBwT[(wm+16+l15)*72+kf];
    aY[0][0] = __builtin_amdgcn_mfma_f32_16x16x32_bf16(s0,b0,aY[0][0],0,0,0);
    aY[0][1] = __builtin_amdgcn_mfma_f32_16x16x32_bf16(s0,b1,aY[0][1],0,0,0);
    aY[1][0] = __builtin_amdgcn_mfma_f32_16x16x32_bf16(s1,b0,aY[1][0],0,0,0);
    aY[1][1] = __builtin_amdgcn_mfma_f32_16x16x32_bf16(s1,b1,aY[1][1],0,0,0);
    aH[0][0] = __builtin_amdgcn_mfma_f32_16x16x32_bf16(w0,b0,aH[0][0],0,0,0);
    aH[0][1] = __builtin_amdgcn_mfma_f32_16x16x32_bf16(w0,b1,aH[0][1],0,0,0);
    aH[1][0] = __builtin_amdgcn_mfma_f32_16x16x32_bf16(w1,b0,aH[1][0],0,0,0);
    aH[1][1] = __builtin_amdgcn_mfma_f32_16x16x32_bf16(w1,b1,aH[1][1],0,0,0);
  }

  const float Dh = dp_[h];
  #pragma unroll
  for (int mi=0;mi<2;++mi)
    #pragma unroll
    for (int ni=0;ni<2;++ni)
      #pragma unroll
      for (int r4=0;r4<4;++r4){
        const int rr = wm+mi*16+quad*4+r4;      // i for Y, n for H
        const int p  = wn+ni*16+l15;
        const float xval = (float)sXT[p*72 + rr];
        xy[((size_t)b*SEQ + t0 + rr)*DI + h*64 + p] = (__bf16)(aY[mi][ni][r4] + Dh*xval);
        gHc[((bh*NC + c)*64 + rr)*64 + p] = (__bf16)aH[mi][ni][r4];
      }
}

// ---------------------------------------------------------------------------
// Chunk recurrence, in place: Hpre[c] (exclusive prefix) overwrites Hc[c].
// ---------------------------------------------------------------------------
__global__ __launch_bounds__(256) void chunk_scan_k(
    __bf16* __restrict__ gHc, const float* __restrict__ g_cs)
{
  const size_t bh = blockIdx.x>>4;
  const int part = blockIdx.x&15;
  const int e = part*256 + threadIdx.x;
  float run = 0.f;
  #pragma unroll
  for (int c=0;c<NC;++c){
    const float lam = __expf(g_cs[bh*SEQ + c*64 + 63]);   // <=1
    const size_t off = (bh*NC + c)*4096 + e;
    const float hc = (float)gHc[off];
    gHc[off] = (__bf16)run;
    run = run*lam + hc;
  }
}

// ---------------------------------------------------------------------------
// Y_inter: y[i][p] += exp(cs_i) * sum_n C[i,n]*Hpre[n,p]   (RMW on xy)
// ---------------------------------------------------------------------------
__global__ __launch_bounds__(256) void ssd_inter_k(
    const __bf16* __restrict__ bc, const __bf16* __restrict__ gHc,
    const float* __restrict__ g_cs, __bf16* __restrict__ xy)
{
  __shared__ __bf16 sCc[64*72], sHT[64*72];
  __shared__ float sE2[64];
  const int bid = blockIdx.x;
  const int h = bid & 15, c = (bid>>4)&7, b = bid>>7;
  const int tid = threadIdx.x, wave = tid>>6, lane = tid&63;
  const int l15 = lane&15, quad = lane>>4;
  const int wm = (wave>>1)*32, wn = (wave&1)*32;
  const int t0 = c*64;
  const size_t bh = (size_t)b*NH + h;

  if (tid < 64) sE2[tid] = __expf(g_cs[bh*SEQ + t0 + tid]);   // <=1
  {
    const int r = tid>>2, seg = (tid&3)*16;
    const __bf16* row = bc + ((size_t)b*SEQ + t0 + r)*128 + 64;
    bf16x8 vc0 = *(const bf16x8*)(row + seg);
    bf16x8 vc1 = *(const bf16x8*)(row + seg + 8);
    *(bf16x8*)&sCc[r*72+seg]   = vc0;
    *(bf16x8*)&sCc[r*72+seg+8] = vc1;
    const __bf16* hrow = gHc + ((bh*NC + c)*64 + r)*64;
    bf16x8 vh0 = *(const bf16x8*)(hrow + seg);
    bf16x8 vh1 = *(const bf16x8*)(hrow + seg + 8);
    #pragma unroll
    for (int e=0;e<8;++e){
      sHT[(seg+e)*72 + r]   = vh0[e];
      sHT[(seg+8+e)*72 + r] = vh1[e];
    }
  }
  __syncthreads();

  f32x4 aY[2][2];
  #pragma unroll
  for (int a=0;a<2;++a)
    #pragma unroll
    for (int d=0;d<2;++d) aY[a][d] = (f32x4){0,0,0,0};
  #pragma unroll
  for (int kk=0; kk<64; kk+=32){
    const int kf = kk + quad*8;
    bf16x8 a0 = *(const bf16x8*)&sCc[(wm+l15)*72+kf];
    bf16x8 a1 = *(const bf16x8*)&sCc[(wm+16+l15)*72+kf];
    bf16x8 b0 = *(const bf16x8*)&sHT[(wn+l15)*72+kf];
    bf16x8 b1 = *(const bf16x8*)&sHT[(wn+16+l15)*72+kf];
    aY[0][0] = __builtin_amdgcn_mfma_f32_16x16x32_bf16(a0,b0,aY[0][0],0,0,0);
    aY[0][1] = __builtin_amdgcn_mfma_f32_16x16x32_bf16(a0,b1,aY[0][1],0,0,0);
    aY[1][0] = __builtin_amdgcn_mfma_f32_16x16x32_bf16(a1,b0,aY[1][0],0,0,0);
    aY[1][1] = __builtin_amdgcn_mfma_f32_16x16x32_bf16(a1,b1,aY[1][1],0,0,0);
  }
  #pragma unroll
  for (int mi=0;mi<2;++mi)
    #pragma unroll
    for (int ni=0;ni<2;++ni)
      #pragma unroll
      for (int r4=0;r4<4;++r4){
        const int i = wm+mi*16+quad*4+r4;
        const int p = wn+ni*16+l15;
        const size_t addr = ((size_t)b*SEQ + t0 + i)*DI + h*64 + p;
        xy[addr] = (__bf16)((float)xy[addr] + sE2[i]*aY[mi][ni][r4]);
      }
}

// ---------------------------------------------------------------------------
__global__ __launch_bounds__(256) void gate_rms_k(
    __bf16* __restrict__ y, const __bf16* __restrict__ z, const float* __restrict__ nw)
{
  __shared__ float red[4];
  const int row = blockIdx.x;
  __bf16* yrow = y + (size_t)row*DI;
  const __bf16* zrow = z + (size_t)row*DI;
  const int tid = threadIdx.x;
  float u[4]; float ss = 0.f;
  #pragma unroll
  for (int j=0;j<4;++j){
    int i = tid + j*256;
    float uu = (float)yrow[i]*siluf_((float)zrow[i]);
    u[j] = uu; ss += uu*uu;
  }
  #pragma unroll
  for (int o=32;o;o>>=1) ss += __shfl_xor(ss,o);
  if ((tid&63)==0) red[tid>>6] = ss;
  __syncthreads();
  ss = red[0]+red[1]+red[2]+red[3];
  const float sc = rsqrtf(ss*(1.f/DI) + EPSF);
  #pragma unroll
  for (int j=0;j<4;++j){
    int i = tid + j*256;
    yrow[i] = (__bf16)(u[j]*sc*nw[i]);
  }
}

// ---------------------------------------------------------------------------
__global__ __launch_bounds__(256) void add_ln_k(
    const __bf16* __restrict__ tmp, __bf16* __restrict__ resio,
    const float* __restrict__ w, const float* __restrict__ bb)
{
  __shared__ float red[4];
  const int row = blockIdx.x;
  const int tid = threadIdx.x;
  const __bf16* trow = tmp + (size_t)row*DM;
  __bf16* rrow = resio + (size_t)row*DM;
  float v0 = (float)trow[tid]     + (float)rrow[tid];
  float v1 = (float)trow[tid+256] + (float)rrow[tid+256];
  float s = v0+v1;
  #pragma unroll
  for (int o=32;o;o>>=1) s += __shfl_xor(s,o);
  if ((tid&63)==0) red[tid>>6] = s;
  __syncthreads();
  s = red[0]+red[1]+red[2]+red[3];
  const float mean = s*(1.f/DM);
  float d0=v0-mean, d1=v1-mean;
  float q = d0*d0 + d1*d1;
  #pragma unroll
  for (int o=32;o;o>>=1) q += __shfl_xor(q,o);
  __syncthreads();
  if ((tid&63)==0) red[tid>>6] = q;
  __syncthreads();
  q = red[0]+red[1]+red[2]+red[3];
  const float rstd = rsqrtf(q*(1.f/DM) + EPSF);
  rrow[tid]     = (__bf16)(d0*rstd*w[tid]     + bb[tid]);
  rrow[tid+256] = (__bf16)(d1*rstd*w[tid+256] + bb[tid+256]);
}

// ---------------------------------------------------------------------------
__global__ __launch_bounds__(256) void gather_k(
    const __bf16* __restrict__ xc, __bf16* __restrict__ g)
{
  int idx = blockIdx.x*256 + threadIdx.x;
  if (idx >= BATCH*PREDN*DM) return;
  int dcol = idx & (DM-1);
  int r = idx >> 9;
  int b = r / PREDN, t = (SEQ-PREDN) + (r % PREDN);
  g[idx] = xc[((size_t)b*SEQ + t)*DM + dcol];
}

// ---------------------------------------------------------------------------
extern "C" void kernel_launch(void* const* d_in, const int* in_sizes, int n_in,
                              void* d_out, int out_size, void* d_ws, size_t ws_size,
                              hipStream_t stream)
{
  const float* x         = (const float*)d_in[0];
  const float* in_proj_w = (const float*)d_in[1];
  const float* conv_w    = (const float*)d_in[2];
  const float* conv_b    = (const float*)d_in[3];
  const float* dt_bias   = (const float*)d_in[4];
  const float* A_log     = (const float*)d_in[5];
  const float* Dp        = (const float*)d_in[6];
  const float* norm_w    = (const float*)d_in[7];
  const float* out_proj_w= (const float*)d_in[8];
  const float* ln_w      = (const float*)d_in[9];
  const float* ln_b      = (const float*)d_in[10];
  const float* final_w   = (const float*)d_in[11];
  const float* final_b   = (const float*)d_in[12];
  float* out = (float*)d_out;

  const size_t ROWS = (size_t)BATCH*SEQ;        // 16384
  __bf16* wbf_in  = (__bf16*)d_ws;
  __bf16* wbf_out = wbf_in  + (size_t)NL*DPROJ*DM;
  __bf16* wbf_fin = wbf_out + (size_t)NL*DM*DI;
  __bf16* zbuf    = wbf_fin + (size_t)DM*DM;
  __bf16* xbw     = zbuf    + ROWS*DI;
  __bf16* ybuf    = xbw     + ROWS*XBW;
  __bf16* bcb     = ybuf    + ROWS*DI;
  __bf16* xcur    = bcb     + ROWS*128;
  float*  g_dt    = (float*)(xcur + ROWS*DM);
  float*  g_cs    = g_dt + (size_t)BATCH*NH*SEQ;
  __bf16* gHc  = xbw;     // alias: xbw dead during scan phase
  __bf16* tmp  = xbw;     // alias: out_proj dest (after scan)
  __bf16* gbuf = bcb;     // alias: gather dest (after layers)

  {
    int n1 = NL*DPROJ*DM, n2 = NL*DM*DI, n3 = DM*DM, n4 = (int)(ROWS*DM);
    cast_bf16_k<<<(n1+255)/256, 256, 0, stream>>>(in_proj_w,  wbf_in,  n1);
    cast_bf16_k<<<(n2+255)/256, 256, 0, stream>>>(out_proj_w, wbf_out, n2);
    cast_bf16_k<<<(n3+255)/256, 256, 0, stream>>>(final_w,    wbf_fin, n3);
    cast_bf16_k<<<(n4+255)/256, 256, 0, stream>>>(x,          xcur,    n4);
  }

  const int convTotal = BATCH*SEQ*CDIM;

  for (int l=0; l<NL; ++l){
    const __bf16* wl = wbf_in + (size_t)l*DPROJ*DM;
    gemm128<__bf16><<<dim3(DI/128, (int)(ROWS/128)), 256, 0, stream>>>(
        xcur, wl, zbuf, nullptr, (int)ROWS, DI, DI, DM);
    gemm128<__bf16><<<dim3(10, (int)(ROWS/128)), 256, 0, stream>>>(
        xcur, wl + (size_t)DI*DM, xbw, nullptr, (int)ROWS, XBW, XBW, DM);
    conv_silu_k<<<(convTotal+255)/256, 256, 0, stream>>>(
        xbw, conv_w + (size_t)l*CDIM*4, conv_b + (size_t)l*CDIM, ybuf, bcb);
    dtcs_k<<<BATCH*NH*NC, 64, 0, stream>>>(
        xbw, dt_bias + l*NH, A_log + l*NH, g_dt, g_cs);
    ssd_chunk_k<<<BATCH*NH*NC, 256, 0, stream>>>(
        bcb, ybuf, g_dt, g_cs, Dp + l*NH, gHc);
    chunk_scan_k<<<BATCH*NH*16, 256, 0, stream>>>(gHc, g_cs);
    ssd_inter_k<<<BATCH*NH*NC, 256, 0, stream>>>(bcb, gHc, g_cs, ybuf);
    gate_rms_k<<<(int)ROWS, 256, 0, stream>>>(ybuf, zbuf, norm_w + (size_t)l*DI);
    gemm128<__bf16><<<dim3(DM/128, (int)(ROWS/128)), 256, 0, stream>>>(
        ybuf, wbf_out + (size_t)l*DM*DI, tmp, nullptr, (int)ROWS, DM, DM, DI);
    add_ln_k<<<(int)ROWS, 256, 0, stream>>>(tmp, xcur, ln_w + l*DM, ln_b + l*DM);
  }
  gather_k<<<(BATCH*PREDN*DM+255)/256, 256, 0, stream>>>(xcur, gbuf);
  gemm128<float><<<dim3(DM/128, (BATCH*PREDN)/128), 256, 0, stream>>>(
      gbuf, wbf_fin, out, final_b, BATCH*PREDN, DM, DM, DM);
}

// Round 5
// 1128.628 us; speedup vs baseline: 3.0693x; 1.1107x over previous
//
#include <hip/hip_runtime.h>
#include <stdint.h>

#define BATCH 32
#define SEQ   512
#define DM    512
#define NL    4
#define DSTATE 64
#define DI    1024   // D_INNER
#define NH    16
#define HD    64
#define PREDN 96
#define CDIM  1152   // DI + 2*DSTATE
#define CSEG  144    // CDIM/8
#define DPROJ 2192
#define XBW   1168   // xBC (1152) + dt (16) columns
#define NC    8      // chunks per sequence
#define EPSF  1e-5f

typedef float  f32x4  __attribute__((ext_vector_type(4)));
typedef __bf16 bf16x4 __attribute__((ext_vector_type(4)));
typedef __bf16 bf16x8 __attribute__((ext_vector_type(8)));

__device__ __forceinline__ float sigmoidf_(float x){ return 1.f/(1.f+__expf(-x)); }
__device__ __forceinline__ float siluf_(float x){ return x*sigmoidf_(x); }
__device__ __forceinline__ float softplusf_(float x){ return (x>20.f)?x:log1pf(__expf(x)); }

// direct global->LDS async copy, 16B per lane
__device__ __forceinline__ void gld16(const void* g, void* l){
  __builtin_amdgcn_global_load_lds((__attribute__((address_space(1))) void*)g,
                                   (__attribute__((address_space(3))) void*)l, 16, 0, 0);
}

// ---------------------------------------------------------------------------
// GEMM (B-transposed): C[M,N] = A[M,K] * W[N,K]^T (+bias). bf16 in, MFMA,
// 128x128 tile, BK=64, global_load_lds staging (m97 structure).
// ---------------------------------------------------------------------------
template<typename TC>
__global__ __launch_bounds__(256) void gemm128(
    const __bf16* __restrict__ A, const __bf16* __restrict__ W,
    TC* __restrict__ C, const float* __restrict__ bias,
    int M, int Nreal, int ldc, int K)
{
  __shared__ __bf16 sA[128*64];
  __shared__ __bf16 sW[128*64];
  const int tid  = threadIdx.x;
  const int m0   = blockIdx.y*128, n0 = blockIdx.x*128;
  const int lane = tid&63, wave = tid>>6;
  const int l15  = lane&15, quad = lane>>4;
  const int wr   = (wave>>1)*64, wc = (wave&1)*64;
  f32x4 acc[4][4];
  #pragma unroll
  for (int a=0;a<4;++a)
    #pragma unroll
    for (int b=0;b<4;++b) acc[a][b] = (f32x4){0,0,0,0};

  for (int k0=0; k0<K; k0+=64){
    #pragma unroll
    for (int j=0;j<4;++j){
      const int f = j*256 + tid;
      const int r = f>>3, kc = (f&7)*8;
      gld16(A + (size_t)(m0+r)*K + k0 + kc, &sA[f*8]);
      int rb = n0 + r; rb = rb < Nreal ? rb : (Nreal-1);
      gld16(W + (size_t)rb*K + k0 + kc, &sW[f*8]);
    }
    __syncthreads();
    #pragma unroll
    for (int kk=0; kk<64; kk+=32){
      const int kf = kk + quad*8;
      bf16x8 av[4], bv[4];
      #pragma unroll
      for (int mi=0;mi<4;++mi) av[mi] = *(const bf16x8*)&sA[(wr+mi*16+l15)*64+kf];
      #pragma unroll
      for (int ni=0;ni<4;++ni) bv[ni] = *(const bf16x8*)&sW[(wc+ni*16+l15)*64+kf];
      #pragma unroll
      for (int mi=0;mi<4;++mi)
        #pragma unroll
        for (int ni=0;ni<4;++ni)
          acc[mi][ni] = __builtin_amdgcn_mfma_f32_16x16x32_bf16(av[mi],bv[ni],acc[mi][ni],0,0,0);
    }
    __syncthreads();
  }
  #pragma unroll
  for (int ni=0;ni<4;++ni){
    const int col = n0 + wc + ni*16 + l15;
    if (col < Nreal){
      const float badd = bias ? bias[col] : 0.f;
      #pragma unroll
      for (int mi=0;mi<4;++mi){
        #pragma unroll
        for (int r4=0;r4<4;++r4){
          const int row = m0 + wr + mi*16 + quad*4 + r4;
          C[(size_t)row*ldc + col] = (TC)(acc[mi][ni][r4] + badd);
        }
      }
    }
  }
}

// ---------------------------------------------------------------------------
// vectorized fp32 -> bf16 cast (n divisible by 4)
// ---------------------------------------------------------------------------
__global__ __launch_bounds__(256) void cast_bf16_k(
    const float* __restrict__ src, __bf16* __restrict__ dst, int n4)
{
  int i = blockIdx.x*256 + threadIdx.x;
  if (i < n4){
    float4 v = ((const float4*)src)[i];
    bf16x4 o;
    o[0]=(__bf16)v.x; o[1]=(__bf16)v.y; o[2]=(__bf16)v.z; o[3]=(__bf16)v.w;
    ((bf16x4*)dst)[i] = o;
  }
}

// ---------------------------------------------------------------------------
// Causal depthwise conv (width 4) + bias + SiLU, 8 channels per thread.
// ---------------------------------------------------------------------------
__global__ __launch_bounds__(256) void conv_silu_k(
    const __bf16* __restrict__ xbw, const float* __restrict__ cw,
    const float* __restrict__ cb, __bf16* __restrict__ xout,
    __bf16* __restrict__ bcout)
{
  int idx = blockIdx.x*256 + threadIdx.x;
  if (idx >= BATCH*SEQ*CSEG) return;
  const int seg = idx % CSEG;
  const int bt  = idx / CSEG;
  const int t = bt % SEQ, b = bt / SEQ;
  const int d0 = seg*8;
  const __bf16* src = xbw + ((size_t)b*SEQ + t)*XBW + d0;
  bf16x8 z8;
  #pragma unroll
  for (int e=0;e<8;++e) z8[e]=(__bf16)0.f;
  bf16x8 x3 = *(const bf16x8*)src;
  bf16x8 x2 = (t>=1)? *(const bf16x8*)(src -   XBW) : z8;
  bf16x8 x1 = (t>=2)? *(const bf16x8*)(src - 2*XBW) : z8;
  bf16x8 x0 = (t>=3)? *(const bf16x8*)(src - 3*XBW) : z8;
  const float4* w4  = (const float4*)(cw + (size_t)d0*4);
  const float4* cb4 = (const float4*)(cb + d0);
  float4 cbl = cb4[0], cbh = cb4[1];
  bf16x8 o;
  #pragma unroll
  for (int e=0;e<8;++e){
    float4 w = w4[e];
    float acc = (e<4 ? (&cbl.x)[e] : (&cbh.x)[e-4])
              + w.x*(float)x0[e] + w.y*(float)x1[e]
              + w.z*(float)x2[e] + w.w*(float)x3[e];
    o[e] = (__bf16)siluf_(acc);
  }
  if (d0 < DI) *(bf16x8*)(xout  + ((size_t)b*SEQ+t)*DI  + d0)       = o;
  else         *(bf16x8*)(bcout + ((size_t)b*SEQ+t)*128 + (d0-DI))  = o;
}

// ---------------------------------------------------------------------------
// dt = softplus(raw+bias); cs = within-chunk inclusive cumsum of dt*A.
// ---------------------------------------------------------------------------
__global__ __launch_bounds__(64) void dtcs_k(
    const __bf16* __restrict__ xbw, const float* __restrict__ dtb_,
    const float* __restrict__ alog_, float* __restrict__ g_dt,
    float* __restrict__ g_cs)
{
  const int bid = blockIdx.x;
  const int c = bid & 7, h = (bid>>3)&15, b = bid>>7;
  const int j = threadIdx.x, t = c*64 + j;
  float raw = (float)xbw[((size_t)b*SEQ + t)*XBW + CDIM + h];
  float dt  = softplusf_(raw + dtb_[h]);
  float s   = dt * (-__expf(alog_[h]));
  #pragma unroll
  for (int off=1; off<64; off<<=1){
    float v = __shfl_up(s, off);
    if (j >= off) s += v;
  }
  const size_t o = ((size_t)b*NH + h)*SEQ + t;
  g_dt[o] = dt; g_cs[o] = s;
}

// ---------------------------------------------------------------------------
// SSD intra-chunk. exp always on the difference (<=0); min-clamp for j>i.
// ---------------------------------------------------------------------------
__global__ __launch_bounds__(256) void ssd_chunk_k(
    const __bf16* __restrict__ bc, __bf16* __restrict__ xy,
    const float* __restrict__ g_dt, const float* __restrict__ g_cs,
    const float* __restrict__ dp_, __bf16* __restrict__ gHc)
{
  __shared__ __bf16 sB[64*72], sC[64*72], sXT[64*72], sBwT[64*72], sS[64*72];
  __shared__ float sCS[64], sDT[64];
  const int bid = blockIdx.x;
  const int h = bid & 15, c = (bid>>4)&7, b = bid>>7;
  const int tid = threadIdx.x, wave = tid>>6, lane = tid&63;
  const int l15 = lane&15, quad = lane>>4;
  const int wm = (wave>>1)*32, wn = (wave&1)*32;
  const int t0 = c*64;
  const size_t bh = (size_t)b*NH + h;

  if (tid < 64){
    sCS[tid] = g_cs[bh*SEQ + t0 + tid];
    sDT[tid] = g_dt[bh*SEQ + t0 + tid];
  }
  __syncthreads();

  {
    const int r = tid>>2, seg = (tid&3)*16;
    const __bf16* row = bc + ((size_t)b*SEQ + t0 + r)*128;
    bf16x8 vb0 = *(const bf16x8*)(row + seg);
    bf16x8 vb1 = *(const bf16x8*)(row + seg + 8);
    bf16x8 vc0 = *(const bf16x8*)(row + 64 + seg);
    bf16x8 vc1 = *(const bf16x8*)(row + 64 + seg + 8);
    *(bf16x8*)&sB[r*72+seg]   = vb0;
    *(bf16x8*)&sB[r*72+seg+8] = vb1;
    *(bf16x8*)&sC[r*72+seg]   = vc0;
    *(bf16x8*)&sC[r*72+seg+8] = vc1;
    const float w = __expf(sCS[63] - sCS[r]) * sDT[r];   // exponent <= 0
    #pragma unroll
    for (int e=0;e<8;++e){
      sBwT[(seg+e)*72 + r]   = (__bf16)(w*(float)vb0[e]);
      sBwT[(seg+8+e)*72 + r] = (__bf16)(w*(float)vb1[e]);
    }
    const __bf16* xrow = xy + ((size_t)b*SEQ + t0 + r)*DI + h*64;
    bf16x8 vx0 = *(const bf16x8*)(xrow + seg);
    bf16x8 vx1 = *(const bf16x8*)(xrow + seg + 8);
    #pragma unroll
    for (int e=0;e<8;++e){
      sXT[(seg+e)*72 + r]   = vx0[e];
      sXT[(seg+8+e)*72 + r] = vx1[e];
    }
  }
  __syncthreads();

  // mm1: S[i][j] = sum_n C[i,n]*B[j,n]
  f32x4 aS[2][2];
  #pragma unroll
  for (int a=0;a<2;++a)
    #pragma unroll
    for (int d=0;d<2;++d) aS[a][d] = (f32x4){0,0,0,0};
  #pragma unroll
  for (int kk=0; kk<64; kk+=32){
    const int kf = kk + quad*8;
    bf16x8 a0 = *(const bf16x8*)&sC[(wm+l15)*72+kf];
    bf16x8 a1 = *(const bf16x8*)&sC[(wm+16+l15)*72+kf];
    bf16x8 b0 = *(const bf16x8*)&sB[(wn+l15)*72+kf];
    bf16x8 b1 = *(const bf16x8*)&sB[(wn+16+l15)*72+kf];
    aS[0][0] = __builtin_amdgcn_mfma_f32_16x16x32_bf16(a0,b0,aS[0][0],0,0,0);
    aS[0][1] = __builtin_amdgcn_mfma_f32_16x16x32_bf16(a0,b1,aS[0][1],0,0,0);
    aS[1][0] = __builtin_amdgcn_mfma_f32_16x16x32_bf16(a1,b0,aS[1][0],0,0,0);
    aS[1][1] = __builtin_amdgcn_mfma_f32_16x16x32_bf16(a1,b1,aS[1][1],0,0,0);
  }
  #pragma unroll
  for (int mi=0;mi<2;++mi)
    #pragma unroll
    for (int ni=0;ni<2;++ni)
      #pragma unroll
      for (int r4=0;r4<4;++r4){
        const int i = wm+mi*16+quad*4+r4, j = wn+ni*16+l15;
        float ed = __expf(fminf(sCS[i]-sCS[j], 0.f)) * sDT[j];
        float v = aS[mi][ni][r4]*ed;
        sS[i*72+j] = (__bf16)((j<=i)? v : 0.f);
      }
  __syncthreads();

  // mm2: Y[i][p] = sum_j S[i,j]*X[j,p];  mm3: H[n][p] = sum_j Bw[j,n]*X[j,p]
  f32x4 aY[2][2], aH[2][2];
  #pragma unroll
  for (int a=0;a<2;++a)
    #pragma unroll
    for (int d=0;d<2;++d){ aY[a][d]=(f32x4){0,0,0,0}; aH[a][d]=(f32x4){0,0,0,0}; }
  #pragma unroll
  for (int kk=0; kk<64; kk+=32){
    const int kf = kk + quad*8;
    bf16x8 b0 = *(const bf16x8*)&sXT[(wn+l15)*72+kf];
    bf16x8 b1 = *(const bf16x8*)&sXT[(wn+16+l15)*72+kf];
    bf16x8 s0 = *(const bf16x8*)&sS[(wm+l15)*72+kf];
    bf16x8 s1 = *(const bf16x8*)&sS[(wm+16+l15)*72+kf];
    bf16x8 w0 = *(const bf16x8*)&sBwT[(wm+l15)*72+kf];
    bf16x8 w1 = *(const bf16x8*)&sBwT[(wm+16+l15)*72+kf];
    aY[0][0] = __builtin_amdgcn_mfma_f32_16x16x32_bf16(s0,b0,aY[0][0],0,0,0);
    aY[0][1] = __builtin_amdgcn_mfma_f32_16x16x32_bf16(s0,b1,aY[0][1],0,0,0);
    aY[1][0] = __builtin_amdgcn_mfma_f32_16x16x32_bf16(s1,b0,aY[1][0],0,0,0);
    aY[1][1] = __builtin_amdgcn_mfma_f32_16x16x32_bf16(s1,b1,aY[1][1],0,0,0);
    aH[0][0] = __builtin_amdgcn_mfma_f32_16x16x32_bf16(w0,b0,aH[0][0],0,0,0);
    aH[0][1] = __builtin_amdgcn_mfma_f32_16x16x32_bf16(w0,b1,aH[0][1],0,0,0);
    aH[1][0] = __builtin_amdgcn_mfma_f32_16x16x32_bf16(w1,b0,aH[1][0],0,0,0);
    aH[1][1] = __builtin_amdgcn_mfma_f32_16x16x32_bf16(w1,b1,aH[1][1],0,0,0);
  }

  const float Dh = dp_[h];
  #pragma unroll
  for (int mi=0;mi<2;++mi)
    #pragma unroll
    for (int ni=0;ni<2;++ni)
      #pragma unroll
      for (int r4=0;r4<4;++r4){
        const int rr = wm+mi*16+quad*4+r4;      // i for Y, n for H
        const int p  = wn+ni*16+l15;
        const float xval = (float)sXT[p*72 + rr];
        xy[((size_t)b*SEQ + t0 + rr)*DI + h*64 + p] = (__bf16)(aY[mi][ni][r4] + Dh*xval);
        gHc[((bh*NC + c)*64 + rr)*64 + p] = (__bf16)aH[mi][ni][r4];
      }
}

// ---------------------------------------------------------------------------
// Chunk recurrence, in place. One block per (b,h); 256 thr x 16 elems, bf16x8.
// ---------------------------------------------------------------------------
__global__ __launch_bounds__(256) void chunk_scan_k(
    __bf16* __restrict__ gHc, const float* __restrict__ g_cs)
{
  const size_t bh = blockIdx.x;
  const int e0 = threadIdx.x*16;
  float run[16];
  #pragma unroll
  for (int e=0;e<16;++e) run[e]=0.f;
  #pragma unroll
  for (int c=0;c<NC;++c){
    const float lam = __expf(g_cs[bh*SEQ + c*64 + 63]);   // <=1
    __bf16* p = gHc + (bh*NC + c)*4096 + e0;
    bf16x8 v0 = *(bf16x8*)p, v1 = *(bf16x8*)(p+8);
    bf16x8 o0, o1;
    #pragma unroll
    for (int e=0;e<8;++e){
      o0[e] = (__bf16)run[e];
      o1[e] = (__bf16)run[e+8];
      run[e]   = run[e]  *lam + (float)v0[e];
      run[e+8] = run[e+8]*lam + (float)v1[e];
    }
    *(bf16x8*)p     = o0;
    *(bf16x8*)(p+8) = o1;
  }
}

// ---------------------------------------------------------------------------
// Y_inter: y[i][p] += exp(cs_i) * sum_n C[i,n]*Hpre[n,p]   (RMW on xy)
// ---------------------------------------------------------------------------
__global__ __launch_bounds__(256) void ssd_inter_k(
    const __bf16* __restrict__ bc, const __bf16* __restrict__ gHc,
    const float* __restrict__ g_cs, __bf16* __restrict__ xy)
{
  __shared__ __bf16 sCc[64*72], sHT[64*72];
  __shared__ float sE2[64];
  const int bid = blockIdx.x;
  const int h = bid & 15, c = (bid>>4)&7, b = bid>>7;
  const int tid = threadIdx.x, wave = tid>>6, lane = tid&63;
  const int l15 = lane&15, quad = lane>>4;
  const int wm = (wave>>1)*32, wn = (wave&1)*32;
  const int t0 = c*64;
  const size_t bh = (size_t)b*NH + h;

  if (tid < 64) sE2[tid] = __expf(g_cs[bh*SEQ + t0 + tid]);   // <=1
  {
    const int r = tid>>2, seg = (tid&3)*16;
    const __bf16* row = bc + ((size_t)b*SEQ + t0 + r)*128 + 64;
    bf16x8 vc0 = *(const bf16x8*)(row + seg);
    bf16x8 vc1 = *(const bf16x8*)(row + seg + 8);
    *(bf16x8*)&sCc[r*72+seg]   = vc0;
    *(bf16x8*)&sCc[r*72+seg+8] = vc1;
    const __bf16* hrow = gHc + ((bh*NC + c)*64 + r)*64;
    bf16x8 vh0 = *(const bf16x8*)(hrow + seg);
    bf16x8 vh1 = *(const bf16x8*)(hrow + seg + 8);
    #pragma unroll
    for (int e=0;e<8;++e){
      sHT[(seg+e)*72 + r]   = vh0[e];
      sHT[(seg+8+e)*72 + r] = vh1[e];
    }
  }
  __syncthreads();

  f32x4 aY[2][2];
  #pragma unroll
  for (int a=0;a<2;++a)
    #pragma unroll
    for (int d=0;d<2;++d) aY[a][d] = (f32x4){0,0,0,0};
  #pragma unroll
  for (int kk=0; kk<64; kk+=32){
    const int kf = kk + quad*8;
    bf16x8 a0 = *(const bf16x8*)&sCc[(wm+l15)*72+kf];
    bf16x8 a1 = *(const bf16x8*)&sCc[(wm+16+l15)*72+kf];
    bf16x8 b0 = *(const bf16x8*)&sHT[(wn+l15)*72+kf];
    bf16x8 b1 = *(const bf16x8*)&sHT[(wn+16+l15)*72+kf];
    aY[0][0] = __builtin_amdgcn_mfma_f32_16x16x32_bf16(a0,b0,aY[0][0],0,0,0);
    aY[0][1] = __builtin_amdgcn_mfma_f32_16x16x32_bf16(a0,b1,aY[0][1],0,0,0);
    aY[1][0] = __builtin_amdgcn_mfma_f32_16x16x32_bf16(a1,b0,aY[1][0],0,0,0);
    aY[1][1] = __builtin_amdgcn_mfma_f32_16x16x32_bf16(a1,b1,aY[1][1],0,0,0);
  }
  #pragma unroll
  for (int mi=0;mi<2;++mi)
    #pragma unroll
    for (int ni=0;ni<2;++ni)
      #pragma unroll
      for (int r4=0;r4<4;++r4){
        const int i = wm+mi*16+quad*4+r4;
        const int p = wn+ni*16+l15;
        const size_t addr = ((size_t)b*SEQ + t0 + i)*DI + h*64 + p;
        xy[addr] = (__bf16)((float)xy[addr] + sE2[i]*aY[mi][ni][r4]);
      }
}

// ---------------------------------------------------------------------------
// gate + rmsnorm, 2 rows per block, bf16x8 vectorized.
// ---------------------------------------------------------------------------
__global__ __launch_bounds__(256) void gate_rms_k(
    __bf16* __restrict__ y, const __bf16* __restrict__ z, const float* __restrict__ nw)
{
  __shared__ float red[4];
  const int tid = threadIdx.x;
  const int sub = tid>>7;                    // row within block
  const int off = (tid&127)*8;
  const size_t row = (size_t)blockIdx.x*2 + sub;
  __bf16* yrow = y + row*DI;
  const __bf16* zrow = z + row*DI;
  bf16x8 yv = *(const bf16x8*)(yrow+off);
  bf16x8 zv = *(const bf16x8*)(zrow+off);
  float u[8]; float ss = 0.f;
  #pragma unroll
  for (int e=0;e<8;++e){
    float uu = (float)yv[e]*siluf_((float)zv[e]);
    u[e]=uu; ss += uu*uu;
  }
  #pragma unroll
  for (int o=32;o;o>>=1) ss += __shfl_xor(ss,o);
  if ((tid&63)==0) red[tid>>6] = ss;
  __syncthreads();
  ss = red[sub*2] + red[sub*2+1];
  const float sc = rsqrtf(ss*(1.f/DI) + EPSF);
  const float4* nw4 = (const float4*)(nw + off);
  float4 n0 = nw4[0], n1 = nw4[1];
  bf16x8 o;
  #pragma unroll
  for (int e=0;e<8;++e)
    o[e] = (__bf16)(u[e]*sc*(e<4 ? (&n0.x)[e] : (&n1.x)[e-4]));
  *(bf16x8*)(yrow+off) = o;
}

// ---------------------------------------------------------------------------
__global__ __launch_bounds__(256) void add_ln_k(
    const __bf16* __restrict__ tmp, __bf16* __restrict__ resio,
    const float* __restrict__ w, const float* __restrict__ bb)
{
  __shared__ float red[4];
  const int row = blockIdx.x;
  const int tid = threadIdx.x;
  const __bf16* trow = tmp + (size_t)row*DM;
  __bf16* rrow = resio + (size_t)row*DM;
  float v0 = (float)trow[tid]     + (float)rrow[tid];
  float v1 = (float)trow[tid+256] + (float)rrow[tid+256];
  float s = v0+v1;
  #pragma unroll
  for (int o=32;o;o>>=1) s += __shfl_xor(s,o);
  if ((tid&63)==0) red[tid>>6] = s;
  __syncthreads();
  s = red[0]+red[1]+red[2]+red[3];
  const float mean = s*(1.f/DM);
  float d0=v0-mean, d1=v1-mean;
  float q = d0*d0 + d1*d1;
  #pragma unroll
  for (int o=32;o;o>>=1) q += __shfl_xor(q,o);
  __syncthreads();
  if ((tid&63)==0) red[tid>>6] = q;
  __syncthreads();
  q = red[0]+red[1]+red[2]+red[3];
  const float rstd = rsqrtf(q*(1.f/DM) + EPSF);
  rrow[tid]     = (__bf16)(d0*rstd*w[tid]     + bb[tid]);
  rrow[tid+256] = (__bf16)(d1*rstd*w[tid+256] + bb[tid+256]);
}

// ---------------------------------------------------------------------------
__global__ __launch_bounds__(256) void gather_k(
    const __bf16* __restrict__ xc, __bf16* __restrict__ g)
{
  int idx = blockIdx.x*256 + threadIdx.x;
  if (idx >= BATCH*PREDN*DM) return;
  int dcol = idx & (DM-1);
  int r = idx >> 9;
  int b = r / PREDN, t = (SEQ-PREDN) + (r % PREDN);
  g[idx] = xc[((size_t)b*SEQ + t)*DM + dcol];
}

// ---------------------------------------------------------------------------
extern "C" void kernel_launch(void* const* d_in, const int* in_sizes, int n_in,
                              void* d_out, int out_size, void* d_ws, size_t ws_size,
                              hipStream_t stream)
{
  const float* x         = (const float*)d_in[0];
  const float* in_proj_w = (const float*)d_in[1];
  const float* conv_w    = (const float*)d_in[2];
  const float* conv_b    = (const float*)d_in[3];
  const float* dt_bias   = (const float*)d_in[4];
  const float* A_log     = (const float*)d_in[5];
  const float* Dp        = (const float*)d_in[6];
  const float* norm_w    = (const float*)d_in[7];
  const float* out_proj_w= (const float*)d_in[8];
  const float* ln_w      = (const float*)d_in[9];
  const float* ln_b      = (const float*)d_in[10];
  const float* final_w   = (const float*)d_in[11];
  const float* final_b   = (const float*)d_in[12];
  float* out = (float*)d_out;

  const size_t ROWS = (size_t)BATCH*SEQ;        // 16384
  __bf16* wbf_in  = (__bf16*)d_ws;
  __bf16* wbf_out = wbf_in  + (size_t)NL*DPROJ*DM;
  __bf16* wbf_fin = wbf_out + (size_t)NL*DM*DI;
  __bf16* zbuf    = wbf_fin + (size_t)DM*DM;
  __bf16* xbw     = zbuf    + ROWS*DI;
  __bf16* ybuf    = xbw     + ROWS*XBW;
  __bf16* bcb     = ybuf    + ROWS*DI;
  __bf16* xcur    = bcb     + ROWS*128;
  float*  g_dt    = (float*)(xcur + ROWS*DM);
  float*  g_cs    = g_dt + (size_t)BATCH*NH*SEQ;
  __bf16* gHc  = xbw;     // alias: xbw dead during scan phase
  __bf16* tmp  = xbw;     // alias: out_proj dest (after scan)
  __bf16* gbuf = bcb;     // alias: gather dest (after layers)

  {
    int n1 = NL*DPROJ*DM/4, n2 = NL*DM*DI/4, n3 = DM*DM/4, n4 = (int)(ROWS*DM/4);
    cast_bf16_k<<<(n1+255)/256, 256, 0, stream>>>(in_proj_w,  wbf_in,  n1);
    cast_bf16_k<<<(n2+255)/256, 256, 0, stream>>>(out_proj_w, wbf_out, n2);
    cast_bf16_k<<<(n3+255)/256, 256, 0, stream>>>(final_w,    wbf_fin, n3);
    cast_bf16_k<<<(n4+255)/256, 256, 0, stream>>>(x,          xcur,    n4);
  }

  const int convTotal = BATCH*SEQ*CSEG;

  for (int l=0; l<NL; ++l){
    const __bf16* wl = wbf_in + (size_t)l*DPROJ*DM;
    gemm128<__bf16><<<dim3(DI/128, (int)(ROWS/128)), 256, 0, stream>>>(
        xcur, wl, zbuf, nullptr, (int)ROWS, DI, DI, DM);
    gemm128<__bf16><<<dim3(10, (int)(ROWS/128)), 256, 0, stream>>>(
        xcur, wl + (size_t)DI*DM, xbw, nullptr, (int)ROWS, XBW, XBW, DM);
    conv_silu_k<<<(convTotal+255)/256, 256, 0, stream>>>(
        xbw, conv_w + (size_t)l*CDIM*4, conv_b + (size_t)l*CDIM, ybuf, bcb);
    dtcs_k<<<BATCH*NH*NC, 64, 0, stream>>>(
        xbw, dt_bias + l*NH, A_log + l*NH, g_dt, g_cs);
    ssd_chunk_k<<<BATCH*NH*NC, 256, 0, stream>>>(
        bcb, ybuf, g_dt, g_cs, Dp + l*NH, gHc);
    chunk_scan_k<<<BATCH*NH, 256, 0, stream>>>(gHc, g_cs);
    ssd_inter_k<<<BATCH*NH*NC, 256, 0, stream>>>(bcb, gHc, g_cs, ybuf);
    gate_rms_k<<<(int)(ROWS/2), 256, 0, stream>>>(ybuf, zbuf, norm_w + (size_t)l*DI);
    gemm128<__bf16><<<dim3(DM/128, (int)(ROWS/128)), 256, 0, stream>>>(
        ybuf, wbf_out + (size_t)l*DM*DI, tmp, nullptr, (int)ROWS, DM, DM, DI);
    add_ln_k<<<(int)ROWS, 256, 0, stream>>>(tmp, xcur, ln_w + l*DM, ln_b + l*DM);
  }
  gather_k<<<(BATCH*PREDN*DM+255)/256, 256, 0, stream>>>(xcur, gbuf);
  gemm128<float><<<dim3(DM/128, (BATCH*PREDN)/128), 256, 0, stream>>>(
      gbuf, wbf_fin, out, final_b, BATCH*PREDN, DM, DM, DM);
}

// Round 6
// 996.865 us; speedup vs baseline: 3.4750x; 1.1322x over previous
//
#include <hip/hip_runtime.h>
#include <stdint.h>

#define BATCH 32
#define SEQ   512
#define DM    512
#define NL    4
#define DSTATE 64
#define DI    1024   // D_INNER
#define NH    16
#define HD    64
#define PREDN 96
#define CDIM  1152   // DI + 2*DSTATE
#define CSEG  144    // CDIM/8
#define DPROJ 2192
#define XBW   1168   // xBC (1152) + dt (16) columns
#define NC    8      // chunks per sequence
#define EPSF  1e-5f

typedef float  f32x4  __attribute__((ext_vector_type(4)));
typedef __bf16 bf16x4 __attribute__((ext_vector_type(4)));
typedef __bf16 bf16x8 __attribute__((ext_vector_type(8)));

__device__ __forceinline__ float sigmoidf_(float x){ return 1.f/(1.f+__expf(-x)); }
__device__ __forceinline__ float siluf_(float x){ return x*sigmoidf_(x); }
__device__ __forceinline__ float softplusf_(float x){ return (x>20.f)?x:log1pf(__expf(x)); }

// direct global->LDS async copy, 16B per lane
__device__ __forceinline__ void gld16(const void* g, void* l){
  __builtin_amdgcn_global_load_lds((__attribute__((address_space(1))) void*)g,
                                   (__attribute__((address_space(3))) void*)l, 16, 0, 0);
}

// ---------------------------------------------------------------------------
// GEMM (B-transposed): bf16 MFMA, 128x128 tile, BK=64, global_load_lds.
// XOR-swizzled LDS layout: slot (r, pB) holds global col-block pB^(r&7);
// reads fetch slot kcb^(row&7).  Kills the 16-way bank conflict of the
// unpadded 128B-row-stride tile (quad lanes now 2-way = free, m136) while
// keeping gld16's contiguous dst and 128B-segment global coalescing.
// Split epilogue: col < splitN -> C (ldc), else -> C2 (ldc2, col-splitN).
// ---------------------------------------------------------------------------
template<typename TC>
__global__ __launch_bounds__(256) void gemm128(
    const __bf16* __restrict__ A, const __bf16* __restrict__ W,
    TC* __restrict__ C, TC* __restrict__ C2, const float* __restrict__ bias,
    int M, int Nreal, int ldc, int ldc2, int splitN, int K)
{
  __shared__ __bf16 sA[128*64];
  __shared__ __bf16 sW[128*64];
  const int tid  = threadIdx.x;
  const int m0   = blockIdx.y*128, n0 = blockIdx.x*128;
  const int lane = tid&63, wave = tid>>6;
  const int l15  = lane&15, quad = lane>>4;
  const int wr   = (wave>>1)*64, wc = (wave&1)*64;
  f32x4 acc[4][4];
  #pragma unroll
  for (int a=0;a<4;++a)
    #pragma unroll
    for (int b=0;b<4;++b) acc[a][b] = (f32x4){0,0,0,0};

  for (int k0=0; k0<K; k0+=64){
    #pragma unroll
    for (int j=0;j<4;++j){
      const int f = j*256 + tid;
      const int r = f>>3;
      const int kc = (((f&7) ^ (r&7)))*8;      // XOR-swizzled source col-block
      gld16(A + (size_t)(m0+r)*K + k0 + kc, &sA[f*8]);
      int rb = n0 + r; rb = rb < Nreal ? rb : (Nreal-1);
      gld16(W + (size_t)rb*K + k0 + kc, &sW[f*8]);
    }
    __syncthreads();
    #pragma unroll
    for (int kk=0; kk<64; kk+=32){
      const int kcb = (kk>>3) + quad;          // logical col-block 0..7
      bf16x8 av[4], bv[4];
      #pragma unroll
      for (int mi=0;mi<4;++mi){
        const int row = wr+mi*16+l15;
        av[mi] = *(const bf16x8*)&sA[row*64 + ((kcb ^ (row&7))<<3)];
      }
      #pragma unroll
      for (int ni=0;ni<4;++ni){
        const int row = wc+ni*16+l15;
        bv[ni] = *(const bf16x8*)&sW[row*64 + ((kcb ^ (row&7))<<3)];
      }
      #pragma unroll
      for (int mi=0;mi<4;++mi)
        #pragma unroll
        for (int ni=0;ni<4;++ni)
          acc[mi][ni] = __builtin_amdgcn_mfma_f32_16x16x32_bf16(av[mi],bv[ni],acc[mi][ni],0,0,0);
    }
    __syncthreads();
  }
  #pragma unroll
  for (int ni=0;ni<4;++ni){
    const int col = n0 + wc + ni*16 + l15;
    if (col < Nreal){
      const float badd = bias ? bias[col] : 0.f;
      #pragma unroll
      for (int mi=0;mi<4;++mi){
        #pragma unroll
        for (int r4=0;r4<4;++r4){
          const int row = m0 + wr + mi*16 + quad*4 + r4;
          const float v = acc[mi][ni][r4] + badd;
          if (col < splitN) C [(size_t)row*ldc  + col]          = (TC)v;
          else              C2[(size_t)row*ldc2 + (col-splitN)] = (TC)v;
        }
      }
    }
  }
}

// ---------------------------------------------------------------------------
__global__ __launch_bounds__(256) void cast_bf16_k(
    const float* __restrict__ src, __bf16* __restrict__ dst, int n4)
{
  int i = blockIdx.x*256 + threadIdx.x;
  if (i < n4){
    float4 v = ((const float4*)src)[i];
    bf16x4 o;
    o[0]=(__bf16)v.x; o[1]=(__bf16)v.y; o[2]=(__bf16)v.z; o[3]=(__bf16)v.w;
    ((bf16x4*)dst)[i] = o;
  }
}

// ---------------------------------------------------------------------------
// Causal depthwise conv (width 4) + bias + SiLU, 8 channels per thread.
// ---------------------------------------------------------------------------
__global__ __launch_bounds__(256) void conv_silu_k(
    const __bf16* __restrict__ xbw, const float* __restrict__ cw,
    const float* __restrict__ cb, __bf16* __restrict__ xout,
    __bf16* __restrict__ bcout)
{
  int idx = blockIdx.x*256 + threadIdx.x;
  if (idx >= BATCH*SEQ*CSEG) return;
  const int seg = idx % CSEG;
  const int bt  = idx / CSEG;
  const int t = bt % SEQ, b = bt / SEQ;
  const int d0 = seg*8;
  const __bf16* src = xbw + ((size_t)b*SEQ + t)*XBW + d0;
  bf16x8 z8;
  #pragma unroll
  for (int e=0;e<8;++e) z8[e]=(__bf16)0.f;
  bf16x8 x3 = *(const bf16x8*)src;
  bf16x8 x2 = (t>=1)? *(const bf16x8*)(src -   XBW) : z8;
  bf16x8 x1 = (t>=2)? *(const bf16x8*)(src - 2*XBW) : z8;
  bf16x8 x0 = (t>=3)? *(const bf16x8*)(src - 3*XBW) : z8;
  const float4* w4  = (const float4*)(cw + (size_t)d0*4);
  const float4* cb4 = (const float4*)(cb + d0);
  float4 cbl = cb4[0], cbh = cb4[1];
  bf16x8 o;
  #pragma unroll
  for (int e=0;e<8;++e){
    float4 w = w4[e];
    float acc = (e<4 ? (&cbl.x)[e] : (&cbh.x)[e-4])
              + w.x*(float)x0[e] + w.y*(float)x1[e]
              + w.z*(float)x2[e] + w.w*(float)x3[e];
    o[e] = (__bf16)siluf_(acc);
  }
  if (d0 < DI) *(bf16x8*)(xout  + ((size_t)b*SEQ+t)*DI  + d0)       = o;
  else         *(bf16x8*)(bcout + ((size_t)b*SEQ+t)*128 + (d0-DI))  = o;
}

// ---------------------------------------------------------------------------
__global__ __launch_bounds__(64) void dtcs_k(
    const __bf16* __restrict__ xbw, const float* __restrict__ dtb_,
    const float* __restrict__ alog_, float* __restrict__ g_dt,
    float* __restrict__ g_cs)
{
  const int bid = blockIdx.x;
  const int c = bid & 7, h = (bid>>3)&15, b = bid>>7;
  const int j = threadIdx.x, t = c*64 + j;
  float raw = (float)xbw[((size_t)b*SEQ + t)*XBW + CDIM + h];
  float dt  = softplusf_(raw + dtb_[h]);
  float s   = dt * (-__expf(alog_[h]));
  #pragma unroll
  for (int off=1; off<64; off<<=1){
    float v = __shfl_up(s, off);
    if (j >= off) s += v;
  }
  const size_t o = ((size_t)b*NH + h)*SEQ + t;
  g_dt[o] = dt; g_cs[o] = s;
}

// ---------------------------------------------------------------------------
// SSD intra-chunk. exp always on the difference (<=0); min-clamp for j>i.
// ---------------------------------------------------------------------------
__global__ __launch_bounds__(256) void ssd_chunk_k(
    const __bf16* __restrict__ bc, __bf16* __restrict__ xy,
    const float* __restrict__ g_dt, const float* __restrict__ g_cs,
    const float* __restrict__ dp_, __bf16* __restrict__ gHc)
{
  __shared__ __bf16 sB[64*72], sC[64*72], sXT[64*72], sBwT[64*72], sS[64*72];
  __shared__ float sCS[64], sDT[64];
  const int bid = blockIdx.x;
  const int h = bid & 15, c = (bid>>4)&7, b = bid>>7;
  const int tid = threadIdx.x, wave = tid>>6, lane = tid&63;
  const int l15 = lane&15, quad = lane>>4;
  const int wm = (wave>>1)*32, wn = (wave&1)*32;
  const int t0 = c*64;
  const size_t bh = (size_t)b*NH + h;

  if (tid < 64){
    sCS[tid] = g_cs[bh*SEQ + t0 + tid];
    sDT[tid] = g_dt[bh*SEQ + t0 + tid];
  }
  __syncthreads();

  {
    const int r = tid>>2, seg = (tid&3)*16;
    const __bf16* row = bc + ((size_t)b*SEQ + t0 + r)*128;
    bf16x8 vb0 = *(const bf16x8*)(row + seg);
    bf16x8 vb1 = *(const bf16x8*)(row + seg + 8);
    bf16x8 vc0 = *(const bf16x8*)(row + 64 + seg);
    bf16x8 vc1 = *(const bf16x8*)(row + 64 + seg + 8);
    *(bf16x8*)&sB[r*72+seg]   = vb0;
    *(bf16x8*)&sB[r*72+seg+8] = vb1;
    *(bf16x8*)&sC[r*72+seg]   = vc0;
    *(bf16x8*)&sC[r*72+seg+8] = vc1;
    const float w = __expf(sCS[63] - sCS[r]) * sDT[r];   // exponent <= 0
    #pragma unroll
    for (int e=0;e<8;++e){
      sBwT[(seg+e)*72 + r]   = (__bf16)(w*(float)vb0[e]);
      sBwT[(seg+8+e)*72 + r] = (__bf16)(w*(float)vb1[e]);
    }
    const __bf16* xrow = xy + ((size_t)b*SEQ + t0 + r)*DI + h*64;
    bf16x8 vx0 = *(const bf16x8*)(xrow + seg);
    bf16x8 vx1 = *(const bf16x8*)(xrow + seg + 8);
    #pragma unroll
    for (int e=0;e<8;++e){
      sXT[(seg+e)*72 + r]   = vx0[e];
      sXT[(seg+8+e)*72 + r] = vx1[e];
    }
  }
  __syncthreads();

  f32x4 aS[2][2];
  #pragma unroll
  for (int a=0;a<2;++a)
    #pragma unroll
    for (int d=0;d<2;++d) aS[a][d] = (f32x4){0,0,0,0};
  #pragma unroll
  for (int kk=0; kk<64; kk+=32){
    const int kf = kk + quad*8;
    bf16x8 a0 = *(const bf16x8*)&sC[(wm+l15)*72+kf];
    bf16x8 a1 = *(const bf16x8*)&sC[(wm+16+l15)*72+kf];
    bf16x8 b0 = *(const bf16x8*)&sB[(wn+l15)*72+kf];
    bf16x8 b1 = *(const bf16x8*)&sB[(wn+16+l15)*72+kf];
    aS[0][0] = __builtin_amdgcn_mfma_f32_16x16x32_bf16(a0,b0,aS[0][0],0,0,0);
    aS[0][1] = __builtin_amdgcn_mfma_f32_16x16x32_bf16(a0,b1,aS[0][1],0,0,0);
    aS[1][0] = __builtin_amdgcn_mfma_f32_16x16x32_bf16(a1,b0,aS[1][0],0,0,0);
    aS[1][1] = __builtin_amdgcn_mfma_f32_16x16x32_bf16(a1,b1,aS[1][1],0,0,0);
  }
  #pragma unroll
  for (int mi=0;mi<2;++mi)
    #pragma unroll
    for (int ni=0;ni<2;++ni)
      #pragma unroll
      for (int r4=0;r4<4;++r4){
        const int i = wm+mi*16+quad*4+r4, j = wn+ni*16+l15;
        float ed = __expf(fminf(sCS[i]-sCS[j], 0.f)) * sDT[j];
        float v = aS[mi][ni][r4]*ed;
        sS[i*72+j] = (__bf16)((j<=i)? v : 0.f);
      }
  __syncthreads();

  f32x4 aY[2][2], aH[2][2];
  #pragma unroll
  for (int a=0;a<2;++a)
    #pragma unroll
    for (int d=0;d<2;++d){ aY[a][d]=(f32x4){0,0,0,0}; aH[a][d]=(f32x4){0,0,0,0}; }
  #pragma unroll
  for (int kk=0; kk<64; kk+=32){
    const int kf = kk + quad*8;
    bf16x8 b0 = *(const bf16x8*)&sXT[(wn+l15)*72+kf];
    bf16x8 b1 = *(const bf16x8*)&sXT[(wn+16+l15)*72+kf];
    bf16x8 s0 = *(const bf16x8*)&sS[(wm+l15)*72+kf];
    bf16x8 s1 = *(const bf16x8*)&sS[(wm+16+l15)*72+kf];
    bf16x8 w0 = *(const bf16x8*)&sBwT[(wm+l15)*72+kf];
    bf16x8 w1 = *(const bf16x8*)&sBwT[(wm+16+l15)*72+kf];
    aY[0][0] = __builtin_amdgcn_mfma_f32_16x16x32_bf16(s0,b0,aY[0][0],0,0,0);
    aY[0][1] = __builtin_amdgcn_mfma_f32_16x16x32_bf16(s0,b1,aY[0][1],0,0,0);
    aY[1][0] = __builtin_amdgcn_mfma_f32_16x16x32_bf16(s1,b0,aY[1][0],0,0,0);
    aY[1][1] = __builtin_amdgcn_mfma_f32_16x16x32_bf16(s1,b1,aY[1][1],0,0,0);
    aH[0][0] = __builtin_amdgcn_mfma_f32_16x16x32_bf16(w0,b0,aH[0][0],0,0,0);
    aH[0][1] = __builtin_amdgcn_mfma_f32_16x16x32_bf16(w0,b1,aH[0][1],0,0,0);
    aH[1][0] = __builtin_amdgcn_mfma_f32_16x16x32_bf16(w1,b0,aH[1][0],0,0,0);
    aH[1][1] = __builtin_amdgcn_mfma_f32_16x16x32_bf16(w1,b1,aH[1][1],0,0,0);
  }

  const float Dh = dp_[h];
  #pragma unroll
  for (int mi=0;mi<2;++mi)
    #pragma unroll
    for (int ni=0;ni<2;++ni)
      #pragma unroll
      for (int r4=0;r4<4;++r4){
        const int rr = wm+mi*16+quad*4+r4;
        const int p  = wn+ni*16+l15;
        const float xval = (float)sXT[p*72 + rr];
        xy[((size_t)b*SEQ + t0 + rr)*DI + h*64 + p] = (__bf16)(aY[mi][ni][r4] + Dh*xval);
        gHc[((bh*NC + c)*64 + rr)*64 + p] = (__bf16)aH[mi][ni][r4];
      }
}

// ---------------------------------------------------------------------------
__global__ __launch_bounds__(256) void chunk_scan_k(
    __bf16* __restrict__ gHc, const float* __restrict__ g_cs)
{
  const size_t bh = blockIdx.x;
  const int e0 = threadIdx.x*16;
  float run[16];
  #pragma unroll
  for (int e=0;e<16;++e) run[e]=0.f;
  #pragma unroll
  for (int c=0;c<NC;++c){
    const float lam = __expf(g_cs[bh*SEQ + c*64 + 63]);   // <=1
    __bf16* p = gHc + (bh*NC + c)*4096 + e0;
    bf16x8 v0 = *(bf16x8*)p, v1 = *(bf16x8*)(p+8);
    bf16x8 o0, o1;
    #pragma unroll
    for (int e=0;e<8;++e){
      o0[e] = (__bf16)run[e];
      o1[e] = (__bf16)run[e+8];
      run[e]   = run[e]  *lam + (float)v0[e];
      run[e+8] = run[e+8]*lam + (float)v1[e];
    }
    *(bf16x8*)p     = o0;
    *(bf16x8*)(p+8) = o1;
  }
}

// ---------------------------------------------------------------------------
__global__ __launch_bounds__(256) void ssd_inter_k(
    const __bf16* __restrict__ bc, const __bf16* __restrict__ gHc,
    const float* __restrict__ g_cs, __bf16* __restrict__ xy)
{
  __shared__ __bf16 sCc[64*72], sHT[64*72];
  __shared__ float sE2[64];
  const int bid = blockIdx.x;
  const int h = bid & 15, c = (bid>>4)&7, b = bid>>7;
  const int tid = threadIdx.x, wave = tid>>6, lane = tid&63;
  const int l15 = lane&15, quad = lane>>4;
  const int wm = (wave>>1)*32, wn = (wave&1)*32;
  const int t0 = c*64;
  const size_t bh = (size_t)b*NH + h;

  if (tid < 64) sE2[tid] = __expf(g_cs[bh*SEQ + t0 + tid]);   // <=1
  {
    const int r = tid>>2, seg = (tid&3)*16;
    const __bf16* row = bc + ((size_t)b*SEQ + t0 + r)*128 + 64;
    bf16x8 vc0 = *(const bf16x8*)(row + seg);
    bf16x8 vc1 = *(const bf16x8*)(row + seg + 8);
    *(bf16x8*)&sCc[r*72+seg]   = vc0;
    *(bf16x8*)&sCc[r*72+seg+8] = vc1;
    const __bf16* hrow = gHc + ((bh*NC + c)*64 + r)*64;
    bf16x8 vh0 = *(const bf16x8*)(hrow + seg);
    bf16x8 vh1 = *(const bf16x8*)(hrow + seg + 8);
    #pragma unroll
    for (int e=0;e<8;++e){
      sHT[(seg+e)*72 + r]   = vh0[e];
      sHT[(seg+8+e)*72 + r] = vh1[e];
    }
  }
  __syncthreads();

  f32x4 aY[2][2];
  #pragma unroll
  for (int a=0;a<2;++a)
    #pragma unroll
    for (int d=0;d<2;++d) aY[a][d] = (f32x4){0,0,0,0};
  #pragma unroll
  for (int kk=0; kk<64; kk+=32){
    const int kf = kk + quad*8;
    bf16x8 a0 = *(const bf16x8*)&sCc[(wm+l15)*72+kf];
    bf16x8 a1 = *(const bf16x8*)&sCc[(wm+16+l15)*72+kf];
    bf16x8 b0 = *(const bf16x8*)&sHT[(wn+l15)*72+kf];
    bf16x8 b1 = *(const bf16x8*)&sHT[(wn+16+l15)*72+kf];
    aY[0][0] = __builtin_amdgcn_mfma_f32_16x16x32_bf16(a0,b0,aY[0][0],0,0,0);
    aY[0][1] = __builtin_amdgcn_mfma_f32_16x16x32_bf16(a0,b1,aY[0][1],0,0,0);
    aY[1][0] = __builtin_amdgcn_mfma_f32_16x16x32_bf16(a1,b0,aY[1][0],0,0,0);
    aY[1][1] = __builtin_amdgcn_mfma_f32_16x16x32_bf16(a1,b1,aY[1][1],0,0,0);
  }
  #pragma unroll
  for (int mi=0;mi<2;++mi)
    #pragma unroll
    for (int ni=0;ni<2;++ni)
      #pragma unroll
      for (int r4=0;r4<4;++r4){
        const int i = wm+mi*16+quad*4+r4;
        const int p = wn+ni*16+l15;
        const size_t addr = ((size_t)b*SEQ + t0 + i)*DI + h*64 + p;
        xy[addr] = (__bf16)((float)xy[addr] + sE2[i]*aY[mi][ni][r4]);
      }
}

// ---------------------------------------------------------------------------
__global__ __launch_bounds__(256) void gate_rms_k(
    __bf16* __restrict__ y, const __bf16* __restrict__ z, const float* __restrict__ nw)
{
  __shared__ float red[4];
  const int tid = threadIdx.x;
  const int sub = tid>>7;
  const int off = (tid&127)*8;
  const size_t row = (size_t)blockIdx.x*2 + sub;
  __bf16* yrow = y + row*DI;
  const __bf16* zrow = z + row*DI;
  bf16x8 yv = *(const bf16x8*)(yrow+off);
  bf16x8 zv = *(const bf16x8*)(zrow+off);
  float u[8]; float ss = 0.f;
  #pragma unroll
  for (int e=0;e<8;++e){
    float uu = (float)yv[e]*siluf_((float)zv[e]);
    u[e]=uu; ss += uu*uu;
  }
  #pragma unroll
  for (int o=32;o;o>>=1) ss += __shfl_xor(ss,o);
  if ((tid&63)==0) red[tid>>6] = ss;
  __syncthreads();
  ss = red[sub*2] + red[sub*2+1];
  const float sc = rsqrtf(ss*(1.f/DI) + EPSF);
  const float4* nw4 = (const float4*)(nw + off);
  float4 n0 = nw4[0], n1 = nw4[1];
  bf16x8 o;
  #pragma unroll
  for (int e=0;e<8;++e)
    o[e] = (__bf16)(u[e]*sc*(e<4 ? (&n0.x)[e] : (&n1.x)[e-4]));
  *(bf16x8*)(yrow+off) = o;
}

// ---------------------------------------------------------------------------
// residual + layernorm, one wave per row (DM=512 = 64 lanes x 8), no LDS.
// ---------------------------------------------------------------------------
__global__ __launch_bounds__(256) void add_ln_k(
    const __bf16* __restrict__ tmp, __bf16* __restrict__ resio,
    const float* __restrict__ w, const float* __restrict__ bb)
{
  const int tid = threadIdx.x, lane = tid&63;
  const size_t row = (size_t)blockIdx.x*4 + (tid>>6);
  const int off = lane*8;
  const __bf16* trow = tmp + row*DM;
  __bf16* rrow = resio + row*DM;
  bf16x8 tv = *(const bf16x8*)(trow+off);
  bf16x8 rv = *(const bf16x8*)(rrow+off);
  float v[8]; float s = 0.f;
  #pragma unroll
  for (int e=0;e<8;++e){ v[e]=(float)tv[e]+(float)rv[e]; s += v[e]; }
  #pragma unroll
  for (int o=32;o;o>>=1) s += __shfl_xor(s,o);
  const float mean = s*(1.f/DM);
  float q = 0.f;
  #pragma unroll
  for (int e=0;e<8;++e){ v[e]-=mean; q += v[e]*v[e]; }
  #pragma unroll
  for (int o=32;o;o>>=1) q += __shfl_xor(q,o);
  const float rstd = rsqrtf(q*(1.f/DM) + EPSF);
  const float4* w4 = (const float4*)(w + off);
  const float4* b4 = (const float4*)(bb + off);
  float4 w0=w4[0], w1=w4[1], b0=b4[0], b1=b4[1];
  bf16x8 o8;
  #pragma unroll
  for (int e=0;e<8;++e){
    float we = e<4 ? (&w0.x)[e] : (&w1.x)[e-4];
    float be = e<4 ? (&b0.x)[e] : (&b1.x)[e-4];
    o8[e] = (__bf16)(v[e]*rstd*we + be);
  }
  *(bf16x8*)(rrow+off) = o8;
}

// ---------------------------------------------------------------------------
__global__ __launch_bounds__(256) void gather_k(
    const __bf16* __restrict__ xc, __bf16* __restrict__ g)
{
  int idx = blockIdx.x*256 + threadIdx.x;
  if (idx >= BATCH*PREDN*DM) return;
  int dcol = idx & (DM-1);
  int r = idx >> 9;
  int b = r / PREDN, t = (SEQ-PREDN) + (r % PREDN);
  g[idx] = xc[((size_t)b*SEQ + t)*DM + dcol];
}

// ---------------------------------------------------------------------------
extern "C" void kernel_launch(void* const* d_in, const int* in_sizes, int n_in,
                              void* d_out, int out_size, void* d_ws, size_t ws_size,
                              hipStream_t stream)
{
  const float* x         = (const float*)d_in[0];
  const float* in_proj_w = (const float*)d_in[1];
  const float* conv_w    = (const float*)d_in[2];
  const float* conv_b    = (const float*)d_in[3];
  const float* dt_bias   = (const float*)d_in[4];
  const float* A_log     = (const float*)d_in[5];
  const float* Dp        = (const float*)d_in[6];
  const float* norm_w    = (const float*)d_in[7];
  const float* out_proj_w= (const float*)d_in[8];
  const float* ln_w      = (const float*)d_in[9];
  const float* ln_b      = (const float*)d_in[10];
  const float* final_w   = (const float*)d_in[11];
  const float* final_b   = (const float*)d_in[12];
  float* out = (float*)d_out;

  const size_t ROWS = (size_t)BATCH*SEQ;        // 16384
  __bf16* wbf_in  = (__bf16*)d_ws;
  __bf16* wbf_out = wbf_in  + (size_t)NL*DPROJ*DM;
  __bf16* wbf_fin = wbf_out + (size_t)NL*DM*DI;
  __bf16* zbuf    = wbf_fin + (size_t)DM*DM;
  __bf16* xbw     = zbuf    + ROWS*DI;
  __bf16* ybuf    = xbw     + ROWS*XBW;
  __bf16* bcb     = ybuf    + ROWS*DI;
  __bf16* xcur    = bcb     + ROWS*128;
  float*  g_dt    = (float*)(xcur + ROWS*DM);
  float*  g_cs    = g_dt + (size_t)BATCH*NH*SEQ;
  __bf16* gHc  = xbw;     // alias: xbw dead during scan phase
  __bf16* tmp  = xbw;     // alias: out_proj dest (after scan)
  __bf16* gbuf = bcb;     // alias: gather dest (after layers)

  {
    int n1 = NL*DPROJ*DM/4, n2 = NL*DM*DI/4, n3 = DM*DM/4, n4 = (int)(ROWS*DM/4);
    cast_bf16_k<<<(n1+255)/256, 256, 0, stream>>>(in_proj_w,  wbf_in,  n1);
    cast_bf16_k<<<(n2+255)/256, 256, 0, stream>>>(out_proj_w, wbf_out, n2);
    cast_bf16_k<<<(n3+255)/256, 256, 0, stream>>>(final_w,    wbf_fin, n3);
    cast_bf16_k<<<(n4+255)/256, 256, 0, stream>>>(x,          xcur,    n4);
  }

  const int convTotal = BATCH*SEQ*CSEG;
  const int BIGN = 1<<30;

  for (int l=0; l<NL; ++l){
    const __bf16* wl = wbf_in + (size_t)l*DPROJ*DM;
    // in_proj, single launch: cols 0..1024 -> zbuf, 1024..2192 -> xbw
    gemm128<__bf16><<<dim3((DPROJ+127)/128, (int)(ROWS/128)), 256, 0, stream>>>(
        xcur, wl, zbuf, xbw, nullptr, (int)ROWS, DPROJ, DI, XBW, DI, DM);
    conv_silu_k<<<(convTotal+255)/256, 256, 0, stream>>>(
        xbw, conv_w + (size_t)l*CDIM*4, conv_b + (size_t)l*CDIM, ybuf, bcb);
    dtcs_k<<<BATCH*NH*NC, 64, 0, stream>>>(
        xbw, dt_bias + l*NH, A_log + l*NH, g_dt, g_cs);
    ssd_chunk_k<<<BATCH*NH*NC, 256, 0, stream>>>(
        bcb, ybuf, g_dt, g_cs, Dp + l*NH, gHc);
    chunk_scan_k<<<BATCH*NH, 256, 0, stream>>>(gHc, g_cs);
    ssd_inter_k<<<BATCH*NH*NC, 256, 0, stream>>>(bcb, gHc, g_cs, ybuf);
    gate_rms_k<<<(int)(ROWS/2), 256, 0, stream>>>(ybuf, zbuf, norm_w + (size_t)l*DI);
    gemm128<__bf16><<<dim3(DM/128, (int)(ROWS/128)), 256, 0, stream>>>(
        ybuf, wbf_out + (size_t)l*DM*DI, tmp, tmp, nullptr, (int)ROWS, DM, DM, DM, BIGN, DI);
    add_ln_k<<<(int)(ROWS/4), 256, 0, stream>>>(tmp, xcur, ln_w + l*DM, ln_b + l*DM);
  }
  gather_k<<<(BATCH*PREDN*DM+255)/256, 256, 0, stream>>>(xcur, gbuf);
  gemm128<float><<<dim3(DM/128, (BATCH*PREDN)/128), 256, 0, stream>>>(
      gbuf, wbf_fin, out, out, final_b, BATCH*PREDN, DM, DM, DM, BIGN, DM);
}

// Round 7
// 893.860 us; speedup vs baseline: 3.8754x; 1.1152x over previous
//
#include <hip/hip_runtime.h>
#include <stdint.h>

#define BATCH 32
#define SEQ   512
#define DM    512
#define NL    4
#define DSTATE 64
#define DI    1024   // D_INNER
#define NH    16
#define HD    64
#define PREDN 96
#define CDIM  1152   // DI + 2*DSTATE
#define CSEG  144    // CDIM/8
#define DPROJ 2192
#define XBW   1168   // xBC (1152) + dt (16) columns
#define NC    8      // chunks per sequence
#define EPSF  1e-5f

typedef float  f32x4  __attribute__((ext_vector_type(4)));
typedef __bf16 bf16x4 __attribute__((ext_vector_type(4)));
typedef __bf16 bf16x8 __attribute__((ext_vector_type(8)));

__device__ __forceinline__ float sigmoidf_(float x){ return 1.f/(1.f+__expf(-x)); }
__device__ __forceinline__ float siluf_(float x){ return x*sigmoidf_(x); }
__device__ __forceinline__ float softplusf_(float x){ return (x>20.f)?x:log1pf(__expf(x)); }

// direct global->LDS async copy, 16B per lane
__device__ __forceinline__ void gld16(const void* g, void* l){
  __builtin_amdgcn_global_load_lds((__attribute__((address_space(1))) void*)g,
                                   (__attribute__((address_space(3))) void*)l, 16, 0, 0);
}

// ---------------------------------------------------------------------------
// GEMM (B-transposed): bf16 MFMA, 128x128 tile, BK=64, global_load_lds,
// XOR-swizzled LDS (R6: killed the 16-way conflict; SQ_LDS_BANK_CONFLICT=0).
// Split epilogue: col < splitN -> C (ldc), else -> C2 (ldc2, col-splitN).
// ---------------------------------------------------------------------------
template<typename TC>
__global__ __launch_bounds__(256) void gemm128(
    const __bf16* __restrict__ A, const __bf16* __restrict__ W,
    TC* __restrict__ C, TC* __restrict__ C2, const float* __restrict__ bias,
    int M, int Nreal, int ldc, int ldc2, int splitN, int K)
{
  __shared__ __bf16 sA[128*64];
  __shared__ __bf16 sW[128*64];
  const int tid  = threadIdx.x;
  const int m0   = blockIdx.y*128, n0 = blockIdx.x*128;
  const int lane = tid&63, wave = tid>>6;
  const int l15  = lane&15, quad = lane>>4;
  const int wr   = (wave>>1)*64, wc = (wave&1)*64;
  f32x4 acc[4][4];
  #pragma unroll
  for (int a=0;a<4;++a)
    #pragma unroll
    for (int b=0;b<4;++b) acc[a][b] = (f32x4){0,0,0,0};

  for (int k0=0; k0<K; k0+=64){
    #pragma unroll
    for (int j=0;j<4;++j){
      const int f = j*256 + tid;
      const int r = f>>3;
      const int kc = (((f&7) ^ (r&7)))*8;      // XOR-swizzled source col-block
      gld16(A + (size_t)(m0+r)*K + k0 + kc, &sA[f*8]);
      int rb = n0 + r; rb = rb < Nreal ? rb : (Nreal-1);
      gld16(W + (size_t)rb*K + k0 + kc, &sW[f*8]);
    }
    __syncthreads();
    #pragma unroll
    for (int kk=0; kk<64; kk+=32){
      const int kcb = (kk>>3) + quad;          // logical col-block 0..7
      bf16x8 av[4], bv[4];
      #pragma unroll
      for (int mi=0;mi<4;++mi){
        const int row = wr+mi*16+l15;
        av[mi] = *(const bf16x8*)&sA[row*64 + ((kcb ^ (row&7))<<3)];
      }
      #pragma unroll
      for (int ni=0;ni<4;++ni){
        const int row = wc+ni*16+l15;
        bv[ni] = *(const bf16x8*)&sW[row*64 + ((kcb ^ (row&7))<<3)];
      }
      #pragma unroll
      for (int mi=0;mi<4;++mi)
        #pragma unroll
        for (int ni=0;ni<4;++ni)
          acc[mi][ni] = __builtin_amdgcn_mfma_f32_16x16x32_bf16(av[mi],bv[ni],acc[mi][ni],0,0,0);
    }
    __syncthreads();
  }
  #pragma unroll
  for (int ni=0;ni<4;++ni){
    const int col = n0 + wc + ni*16 + l15;
    if (col < Nreal){
      const float badd = bias ? bias[col] : 0.f;
      #pragma unroll
      for (int mi=0;mi<4;++mi){
        #pragma unroll
        for (int r4=0;r4<4;++r4){
          const int row = m0 + wr + mi*16 + quad*4 + r4;
          const float v = acc[mi][ni][r4] + badd;
          if (col < splitN) C [(size_t)row*ldc  + col]          = (TC)v;
          else              C2[(size_t)row*ldc2 + (col-splitN)] = (TC)v;
        }
      }
    }
  }
}

// ---------------------------------------------------------------------------
__global__ __launch_bounds__(256) void cast_bf16_k(
    const float* __restrict__ src, __bf16* __restrict__ dst, int n4)
{
  int i = blockIdx.x*256 + threadIdx.x;
  if (i < n4){
    float4 v = ((const float4*)src)[i];
    bf16x4 o;
    o[0]=(__bf16)v.x; o[1]=(__bf16)v.y; o[2]=(__bf16)v.z; o[3]=(__bf16)v.w;
    ((bf16x4*)dst)[i] = o;
  }
}

// ---------------------------------------------------------------------------
// Causal depthwise conv (width 4) + bias + SiLU, 8 channels per thread.
// ---------------------------------------------------------------------------
__global__ __launch_bounds__(256) void conv_silu_k(
    const __bf16* __restrict__ xbw, const float* __restrict__ cw,
    const float* __restrict__ cb, __bf16* __restrict__ xout,
    __bf16* __restrict__ bcout)
{
  int idx = blockIdx.x*256 + threadIdx.x;
  if (idx >= BATCH*SEQ*CSEG) return;
  const int seg = idx % CSEG;
  const int bt  = idx / CSEG;
  const int t = bt % SEQ, b = bt / SEQ;
  const int d0 = seg*8;
  const __bf16* src = xbw + ((size_t)b*SEQ + t)*XBW + d0;
  bf16x8 z8;
  #pragma unroll
  for (int e=0;e<8;++e) z8[e]=(__bf16)0.f;
  bf16x8 x3 = *(const bf16x8*)src;
  bf16x8 x2 = (t>=1)? *(const bf16x8*)(src -   XBW) : z8;
  bf16x8 x1 = (t>=2)? *(const bf16x8*)(src - 2*XBW) : z8;
  bf16x8 x0 = (t>=3)? *(const bf16x8*)(src - 3*XBW) : z8;
  const float4* w4  = (const float4*)(cw + (size_t)d0*4);
  const float4* cb4 = (const float4*)(cb + d0);
  float4 cbl = cb4[0], cbh = cb4[1];
  bf16x8 o;
  #pragma unroll
  for (int e=0;e<8;++e){
    float4 w = w4[e];
    float acc = (e<4 ? (&cbl.x)[e] : (&cbh.x)[e-4])
              + w.x*(float)x0[e] + w.y*(float)x1[e]
              + w.z*(float)x2[e] + w.w*(float)x3[e];
    o[e] = (__bf16)siluf_(acc);
  }
  if (d0 < DI) *(bf16x8*)(xout  + ((size_t)b*SEQ+t)*DI  + d0)       = o;
  else         *(bf16x8*)(bcout + ((size_t)b*SEQ+t)*128 + (d0-DI))  = o;
}

// ---------------------------------------------------------------------------
// Fused SSD: one block per (b,h). Phase 0 computes dt + per-chunk cumsum in
// LDS; then chunks run sequentially with inter-chunk state `run` held in fp32
// registers (C/D fragment layout). Per chunk: S=C@B^T (decay/mask applied on
// the exp of DIFFERENCES, <=0), Y_intra=S@X, Hc=Bw^T@X, Y_inter=Cc@run^T
// (run round-tripped through LDS into B-operand layout), single y write, then
// run = run*lam + Hc. No gHc global buffer, no y RMW.
// ---------------------------------------------------------------------------
__global__ __launch_bounds__(256) void ssd_fused_k(
    const __bf16* __restrict__ bc,     // (B,SEQ,128) conv'd B,C
    __bf16* __restrict__ xy,           // (B,SEQ,DI): in conv'd x, out y
    const __bf16* __restrict__ xbw,    // raw dt columns
    const float* __restrict__ dtb_, const float* __restrict__ alog_,
    const float* __restrict__ dp_)
{
  __shared__ __bf16 sB[64*72], sC[64*72], sXT[64*72], sBwT[64*72],
                    sS[64*72], sHT[64*72];
  __shared__ float sCS[SEQ], sDT[SEQ];
  const int bid = blockIdx.x;
  const int h = bid & 15, b = bid >> 4;
  const int tid = threadIdx.x, wave = tid>>6, lane = tid&63;
  const int l15 = lane&15, quad = lane>>4;
  const int wm = (wave>>1)*32, wn = (wave&1)*32;

  const float Ah  = -__expf(alog_[h]);
  const float dtb = dtb_[h];
  const float Dh  = dp_[h];

  // ---- phase 0: dt + within-chunk inclusive cumsum for all chunks ----
  for (int t = tid; t < SEQ; t += 256){
    float raw = (float)xbw[((size_t)b*SEQ + t)*XBW + CDIM + h];
    float dt = softplusf_(raw + dtb);
    sDT[t] = dt;
    sCS[t] = dt*Ah;
  }
  __syncthreads();
  for (int ch = wave; ch < NC; ch += 4){
    float s = sCS[ch*64 + lane];
    #pragma unroll
    for (int off=1; off<64; off<<=1){
      float v = __shfl_up(s, off);
      if (lane >= off) s += v;
    }
    sCS[ch*64 + lane] = s;
  }
  __syncthreads();

  // inter-chunk state, C/D layout: p = wn+ni*16+l15, n = wm+mi*16+quad*4+r4
  f32x4 run[2][2];
  #pragma unroll
  for (int a=0;a<2;++a)
    #pragma unroll
    for (int d=0;d<2;++d) run[a][d] = (f32x4){0,0,0,0};

  for (int c = 0; c < NC; ++c){
    const int t0 = c*64;
    // ---- staging ----
    {
      const int r = tid>>2, seg = (tid&3)*16;
      const __bf16* row = bc + ((size_t)b*SEQ + t0 + r)*128;
      bf16x8 vb0 = *(const bf16x8*)(row + seg);
      bf16x8 vb1 = *(const bf16x8*)(row + seg + 8);
      bf16x8 vc0 = *(const bf16x8*)(row + 64 + seg);
      bf16x8 vc1 = *(const bf16x8*)(row + 64 + seg + 8);
      *(bf16x8*)&sB[r*72+seg]   = vb0;
      *(bf16x8*)&sB[r*72+seg+8] = vb1;
      *(bf16x8*)&sC[r*72+seg]   = vc0;
      *(bf16x8*)&sC[r*72+seg+8] = vc1;
      const float w = __expf(sCS[t0+63] - sCS[t0+r]) * sDT[t0+r];  // <=0 exp
      #pragma unroll
      for (int e=0;e<8;++e){
        sBwT[(seg+e)*72 + r]   = (__bf16)(w*(float)vb0[e]);
        sBwT[(seg+8+e)*72 + r] = (__bf16)(w*(float)vb1[e]);
      }
      const __bf16* xrow = xy + ((size_t)b*SEQ + t0 + r)*DI + h*64;
      bf16x8 vx0 = *(const bf16x8*)(xrow + seg);
      bf16x8 vx1 = *(const bf16x8*)(xrow + seg + 8);
      #pragma unroll
      for (int e=0;e<8;++e){
        sXT[(seg+e)*72 + r]   = vx0[e];
        sXT[(seg+8+e)*72 + r] = vx1[e];
      }
    }
    __syncthreads();

    // ---- mm1: S[i][j] = sum_n C[i,n]*B[j,n] ----
    f32x4 aS[2][2];
    #pragma unroll
    for (int a=0;a<2;++a)
      #pragma unroll
      for (int d=0;d<2;++d) aS[a][d] = (f32x4){0,0,0,0};
    #pragma unroll
    for (int kk=0; kk<64; kk+=32){
      const int kf = kk + quad*8;
      bf16x8 a0 = *(const bf16x8*)&sC[(wm+l15)*72+kf];
      bf16x8 a1 = *(const bf16x8*)&sC[(wm+16+l15)*72+kf];
      bf16x8 b0 = *(const bf16x8*)&sB[(wn+l15)*72+kf];
      bf16x8 b1 = *(const bf16x8*)&sB[(wn+16+l15)*72+kf];
      aS[0][0] = __builtin_amdgcn_mfma_f32_16x16x32_bf16(a0,b0,aS[0][0],0,0,0);
      aS[0][1] = __builtin_amdgcn_mfma_f32_16x16x32_bf16(a0,b1,aS[0][1],0,0,0);
      aS[1][0] = __builtin_amdgcn_mfma_f32_16x16x32_bf16(a1,b0,aS[1][0],0,0,0);
      aS[1][1] = __builtin_amdgcn_mfma_f32_16x16x32_bf16(a1,b1,aS[1][1],0,0,0);
    }
    // mask + decay -> sS; dump current run -> sHT (B-operand layout)
    #pragma unroll
    for (int mi=0;mi<2;++mi)
      #pragma unroll
      for (int ni=0;ni<2;++ni)
        #pragma unroll
        for (int r4=0;r4<4;++r4){
          const int i = wm+mi*16+quad*4+r4, j = wn+ni*16+l15;
          float ed = __expf(fminf(sCS[t0+i]-sCS[t0+j], 0.f)) * sDT[t0+j];
          float v = aS[mi][ni][r4]*ed;
          sS[i*72+j] = (__bf16)((j<=i)? v : 0.f);
          sHT[j*72+i] = (__bf16)run[mi][ni][r4];   // [p][n]
        }
    __syncthreads();

    // ---- mm2: Y_intra = S@X, H = Bw^T@X, Y_inter = Cc@run^T ----
    f32x4 aY[2][2], aH[2][2], aYi[2][2];
    #pragma unroll
    for (int a=0;a<2;++a)
      #pragma unroll
      for (int d=0;d<2;++d){
        aY[a][d]=(f32x4){0,0,0,0}; aH[a][d]=(f32x4){0,0,0,0};
        aYi[a][d]=(f32x4){0,0,0,0};
      }
    #pragma unroll
    for (int kk=0; kk<64; kk+=32){
      const int kf = kk + quad*8;
      bf16x8 b0 = *(const bf16x8*)&sXT[(wn+l15)*72+kf];
      bf16x8 b1 = *(const bf16x8*)&sXT[(wn+16+l15)*72+kf];
      bf16x8 s0 = *(const bf16x8*)&sS[(wm+l15)*72+kf];
      bf16x8 s1 = *(const bf16x8*)&sS[(wm+16+l15)*72+kf];
      bf16x8 w0 = *(const bf16x8*)&sBwT[(wm+l15)*72+kf];
      bf16x8 w1 = *(const bf16x8*)&sBwT[(wm+16+l15)*72+kf];
      bf16x8 c0 = *(const bf16x8*)&sC[(wm+l15)*72+kf];
      bf16x8 c1 = *(const bf16x8*)&sC[(wm+16+l15)*72+kf];
      bf16x8 h0 = *(const bf16x8*)&sHT[(wn+l15)*72+kf];
      bf16x8 h1 = *(const bf16x8*)&sHT[(wn+16+l15)*72+kf];
      aY[0][0] = __builtin_amdgcn_mfma_f32_16x16x32_bf16(s0,b0,aY[0][0],0,0,0);
      aY[0][1] = __builtin_amdgcn_mfma_f32_16x16x32_bf16(s0,b1,aY[0][1],0,0,0);
      aY[1][0] = __builtin_amdgcn_mfma_f32_16x16x32_bf16(s1,b0,aY[1][0],0,0,0);
      aY[1][1] = __builtin_amdgcn_mfma_f32_16x16x32_bf16(s1,b1,aY[1][1],0,0,0);
      aH[0][0] = __builtin_amdgcn_mfma_f32_16x16x32_bf16(w0,b0,aH[0][0],0,0,0);
      aH[0][1] = __builtin_amdgcn_mfma_f32_16x16x32_bf16(w0,b1,aH[0][1],0,0,0);
      aH[1][0] = __builtin_amdgcn_mfma_f32_16x16x32_bf16(w1,b0,aH[1][0],0,0,0);
      aH[1][1] = __builtin_amdgcn_mfma_f32_16x16x32_bf16(w1,b1,aH[1][1],0,0,0);
      aYi[0][0] = __builtin_amdgcn_mfma_f32_16x16x32_bf16(c0,h0,aYi[0][0],0,0,0);
      aYi[0][1] = __builtin_amdgcn_mfma_f32_16x16x32_bf16(c0,h1,aYi[0][1],0,0,0);
      aYi[1][0] = __builtin_amdgcn_mfma_f32_16x16x32_bf16(c1,h0,aYi[1][0],0,0,0);
      aYi[1][1] = __builtin_amdgcn_mfma_f32_16x16x32_bf16(c1,h1,aYi[1][1],0,0,0);
    }

    // ---- epilogue: single y write + run update ----
    const float lam = __expf(sCS[t0+63]);
    #pragma unroll
    for (int mi=0;mi<2;++mi)
      #pragma unroll
      for (int ni=0;ni<2;++ni)
        #pragma unroll
        for (int r4=0;r4<4;++r4){
          const int i = wm+mi*16+quad*4+r4;
          const int p = wn+ni*16+l15;
          const float xval = (float)sXT[p*72 + i];
          const float e2 = __expf(sCS[t0+i]);    // <=1 (cs<=0)
          const float yv = aY[mi][ni][r4] + Dh*xval + e2*aYi[mi][ni][r4];
          xy[((size_t)b*SEQ + t0 + i)*DI + h*64 + p] = (__bf16)yv;
          run[mi][ni][r4] = run[mi][ni][r4]*lam + aH[mi][ni][r4];
        }
    __syncthreads();   // protect LDS before next chunk's staging
  }
}

// ---------------------------------------------------------------------------
__global__ __launch_bounds__(256) void gate_rms_k(
    __bf16* __restrict__ y, const __bf16* __restrict__ z, const float* __restrict__ nw)
{
  __shared__ float red[4];
  const int tid = threadIdx.x;
  const int sub = tid>>7;
  const int off = (tid&127)*8;
  const size_t row = (size_t)blockIdx.x*2 + sub;
  __bf16* yrow = y + row*DI;
  const __bf16* zrow = z + row*DI;
  bf16x8 yv = *(const bf16x8*)(yrow+off);
  bf16x8 zv = *(const bf16x8*)(zrow+off);
  float u[8]; float ss = 0.f;
  #pragma unroll
  for (int e=0;e<8;++e){
    float uu = (float)yv[e]*siluf_((float)zv[e]);
    u[e]=uu; ss += uu*uu;
  }
  #pragma unroll
  for (int o=32;o;o>>=1) ss += __shfl_xor(ss,o);
  if ((tid&63)==0) red[tid>>6] = ss;
  __syncthreads();
  ss = red[sub*2] + red[sub*2+1];
  const float sc = rsqrtf(ss*(1.f/DI) + EPSF);
  const float4* nw4 = (const float4*)(nw + off);
  float4 n0 = nw4[0], n1 = nw4[1];
  bf16x8 o;
  #pragma unroll
  for (int e=0;e<8;++e)
    o[e] = (__bf16)(u[e]*sc*(e<4 ? (&n0.x)[e] : (&n1.x)[e-4]));
  *(bf16x8*)(yrow+off) = o;
}

// ---------------------------------------------------------------------------
// residual + layernorm, one wave per row (DM=512 = 64 lanes x 8), no LDS.
// ---------------------------------------------------------------------------
__global__ __launch_bounds__(256) void add_ln_k(
    const __bf16* __restrict__ tmp, __bf16* __restrict__ resio,
    const float* __restrict__ w, const float* __restrict__ bb)
{
  const int tid = threadIdx.x, lane = tid&63;
  const size_t row = (size_t)blockIdx.x*4 + (tid>>6);
  const int off = lane*8;
  const __bf16* trow = tmp + row*DM;
  __bf16* rrow = resio + row*DM;
  bf16x8 tv = *(const bf16x8*)(trow+off);
  bf16x8 rv = *(const bf16x8*)(rrow+off);
  float v[8]; float s = 0.f;
  #pragma unroll
  for (int e=0;e<8;++e){ v[e]=(float)tv[e]+(float)rv[e]; s += v[e]; }
  #pragma unroll
  for (int o=32;o;o>>=1) s += __shfl_xor(s,o);
  const float mean = s*(1.f/DM);
  float q = 0.f;
  #pragma unroll
  for (int e=0;e<8;++e){ v[e]-=mean; q += v[e]*v[e]; }
  #pragma unroll
  for (int o=32;o;o>>=1) q += __shfl_xor(q,o);
  const float rstd = rsqrtf(q*(1.f/DM) + EPSF);
  const float4* w4 = (const float4*)(w + off);
  const float4* b4 = (const float4*)(bb + off);
  float4 w0=w4[0], w1=w4[1], b0=b4[0], b1=b4[1];
  bf16x8 o8;
  #pragma unroll
  for (int e=0;e<8;++e){
    float we = e<4 ? (&w0.x)[e] : (&w1.x)[e-4];
    float be = e<4 ? (&b0.x)[e] : (&b1.x)[e-4];
    o8[e] = (__bf16)(v[e]*rstd*we + be);
  }
  *(bf16x8*)(rrow+off) = o8;
}

// ---------------------------------------------------------------------------
__global__ __launch_bounds__(256) void gather_k(
    const __bf16* __restrict__ xc, __bf16* __restrict__ g)
{
  int idx = blockIdx.x*256 + threadIdx.x;
  if (idx >= BATCH*PREDN*DM) return;
  int dcol = idx & (DM-1);
  int r = idx >> 9;
  int b = r / PREDN, t = (SEQ-PREDN) + (r % PREDN);
  g[idx] = xc[((size_t)b*SEQ + t)*DM + dcol];
}

// ---------------------------------------------------------------------------
extern "C" void kernel_launch(void* const* d_in, const int* in_sizes, int n_in,
                              void* d_out, int out_size, void* d_ws, size_t ws_size,
                              hipStream_t stream)
{
  const float* x         = (const float*)d_in[0];
  const float* in_proj_w = (const float*)d_in[1];
  const float* conv_w    = (const float*)d_in[2];
  const float* conv_b    = (const float*)d_in[3];
  const float* dt_bias   = (const float*)d_in[4];
  const float* A_log     = (const float*)d_in[5];
  const float* Dp        = (const float*)d_in[6];
  const float* norm_w    = (const float*)d_in[7];
  const float* out_proj_w= (const float*)d_in[8];
  const float* ln_w      = (const float*)d_in[9];
  const float* ln_b      = (const float*)d_in[10];
  const float* final_w   = (const float*)d_in[11];
  const float* final_b   = (const float*)d_in[12];
  float* out = (float*)d_out;

  const size_t ROWS = (size_t)BATCH*SEQ;        // 16384
  __bf16* wbf_in  = (__bf16*)d_ws;
  __bf16* wbf_out = wbf_in  + (size_t)NL*DPROJ*DM;
  __bf16* wbf_fin = wbf_out + (size_t)NL*DM*DI;
  __bf16* zbuf    = wbf_fin + (size_t)DM*DM;
  __bf16* xbw     = zbuf    + ROWS*DI;
  __bf16* ybuf    = xbw     + ROWS*XBW;
  __bf16* bcb     = ybuf    + ROWS*DI;
  __bf16* xcur    = bcb     + ROWS*128;
  __bf16* tmp  = xbw;     // alias: xbw dead after ssd_fused reads dt
  __bf16* gbuf = bcb;     // alias: gather dest (after layers)

  {
    int n1 = NL*DPROJ*DM/4, n2 = NL*DM*DI/4, n3 = DM*DM/4, n4 = (int)(ROWS*DM/4);
    cast_bf16_k<<<(n1+255)/256, 256, 0, stream>>>(in_proj_w,  wbf_in,  n1);
    cast_bf16_k<<<(n2+255)/256, 256, 0, stream>>>(out_proj_w, wbf_out, n2);
    cast_bf16_k<<<(n3+255)/256, 256, 0, stream>>>(final_w,    wbf_fin, n3);
    cast_bf16_k<<<(n4+255)/256, 256, 0, stream>>>(x,          xcur,    n4);
  }

  const int convTotal = BATCH*SEQ*CSEG;
  const int BIGN = 1<<30;

  for (int l=0; l<NL; ++l){
    const __bf16* wl = wbf_in + (size_t)l*DPROJ*DM;
    // in_proj, single launch: cols 0..1024 -> zbuf, 1024..2192 -> xbw
    gemm128<__bf16><<<dim3((DPROJ+127)/128, (int)(ROWS/128)), 256, 0, stream>>>(
        xcur, wl, zbuf, xbw, nullptr, (int)ROWS, DPROJ, DI, XBW, DI, DM);
    conv_silu_k<<<(convTotal+255)/256, 256, 0, stream>>>(
        xbw, conv_w + (size_t)l*CDIM*4, conv_b + (size_t)l*CDIM, ybuf, bcb);
    // fused SSD: intra + recurrence + inter, y in place on ybuf
    ssd_fused_k<<<BATCH*NH, 256, 0, stream>>>(
        bcb, ybuf, xbw, dt_bias + l*NH, A_log + l*NH, Dp + l*NH);
    gate_rms_k<<<(int)(ROWS/2), 256, 0, stream>>>(ybuf, zbuf, norm_w + (size_t)l*DI);
    gemm128<__bf16><<<dim3(DM/128, (int)(ROWS/128)), 256, 0, stream>>>(
        ybuf, wbf_out + (size_t)l*DM*DI, tmp, tmp, nullptr, (int)ROWS, DM, DM, DM, BIGN, DI);
    add_ln_k<<<(int)(ROWS/4), 256, 0, stream>>>(tmp, xcur, ln_w + l*DM, ln_b + l*DM);
  }
  gather_k<<<(BATCH*PREDN*DM+255)/256, 256, 0, stream>>>(xcur, gbuf);
  gemm128<float><<<dim3(DM/128, (BATCH*PREDN)/128), 256, 0, stream>>>(
      gbuf, wbf_fin, out, out, final_b, BATCH*PREDN, DM, DM, DM, BIGN, DM);
}

// Round 8
// 866.043 us; speedup vs baseline: 3.9999x; 1.0321x over previous
//
#include <hip/hip_runtime.h>
#include <stdint.h>

#define BATCH 32
#define SEQ   512
#define DM    512
#define NL    4
#define DSTATE 64
#define DI    1024   // D_INNER
#define NH    16
#define HD    64
#define PREDN 96
#define CDIM  1152   // DI + 2*DSTATE
#define CSEG  144    // CDIM/8
#define DPROJ 2192
#define XBW   1168   // xBC (1152) + dt (16) columns
#define NC    8      // chunks per sequence
#define EPSF  1e-5f

typedef float  f32x4  __attribute__((ext_vector_type(4)));
typedef __bf16 bf16x4 __attribute__((ext_vector_type(4)));
typedef __bf16 bf16x8 __attribute__((ext_vector_type(8)));

__device__ __forceinline__ float sigmoidf_(float x){ return 1.f/(1.f+__expf(-x)); }
__device__ __forceinline__ float siluf_(float x){ return x*sigmoidf_(x); }
__device__ __forceinline__ float softplusf_(float x){ return (x>20.f)?x:log1pf(__expf(x)); }

// direct global->LDS async copy, 16B per lane
__device__ __forceinline__ void gld16(const void* g, void* l){
  __builtin_amdgcn_global_load_lds((__attribute__((address_space(1))) void*)g,
                                   (__attribute__((address_space(3))) void*)l, 16, 0, 0);
}

// ---------------------------------------------------------------------------
// GEMM (B-transposed): bf16 MFMA, 128x128 tile, BK=64, global_load_lds,
// XOR-swizzled LDS (R6: SQ_LDS_BANK_CONFLICT=0).
// bf16 epilogue (R7): LDS-bounce -> coalesced bf16x8 stores (WRITE_SIZE fix).
// Split epilogue: col < splitN -> C (ldc), else -> C2 (ldc2, col-splitN).
// remapA: A-row r reads global row (r/PREDN)*SEQ + (SEQ-PREDN) + r%PREDN
// (fuses the tail-gather for the final head).
// ---------------------------------------------------------------------------
template<typename TC>
__global__ __launch_bounds__(256) void gemm128(
    const __bf16* __restrict__ A, const __bf16* __restrict__ W,
    TC* __restrict__ C, TC* __restrict__ C2, const float* __restrict__ bias,
    int M, int Nreal, int ldc, int ldc2, int splitN, int K, int remapA)
{
  __shared__ __bf16 sAB[2*128*64];     // K-loop: sA | sW ; epilogue: 128x128 tile
  __bf16* sA = sAB;
  __bf16* sW = sAB + 128*64;
  const int tid  = threadIdx.x;
  const int m0   = blockIdx.y*128, n0 = blockIdx.x*128;
  const int lane = tid&63, wave = tid>>6;
  const int l15  = lane&15, quad = lane>>4;
  const int wr   = (wave>>1)*64, wc = (wave&1)*64;
  f32x4 acc[4][4];
  #pragma unroll
  for (int a=0;a<4;++a)
    #pragma unroll
    for (int b=0;b<4;++b) acc[a][b] = (f32x4){0,0,0,0};

  for (int k0=0; k0<K; k0+=64){
    #pragma unroll
    for (int j=0;j<4;++j){
      const int f = j*256 + tid;
      const int r = f>>3;
      const int kc = (((f&7) ^ (r&7)))*8;      // XOR-swizzled source col-block
      int ga = m0 + r;
      if (remapA){ int bb = ga/PREDN; ga = bb*SEQ + (SEQ-PREDN) + (ga - bb*PREDN); }
      gld16(A + (size_t)ga*K + k0 + kc, &sA[f*8]);
      int rb = n0 + r; rb = rb < Nreal ? rb : (Nreal-1);
      gld16(W + (size_t)rb*K + k0 + kc, &sW[f*8]);
    }
    __syncthreads();
    #pragma unroll
    for (int kk=0; kk<64; kk+=32){
      const int kcb = (kk>>3) + quad;          // logical col-block 0..7
      bf16x8 av[4], bv[4];
      #pragma unroll
      for (int mi=0;mi<4;++mi){
        const int row = wr+mi*16+l15;
        av[mi] = *(const bf16x8*)&sA[row*64 + ((kcb ^ (row&7))<<3)];
      }
      #pragma unroll
      for (int ni=0;ni<4;++ni){
        const int row = wc+ni*16+l15;
        bv[ni] = *(const bf16x8*)&sW[row*64 + ((kcb ^ (row&7))<<3)];
      }
      #pragma unroll
      for (int mi=0;mi<4;++mi)
        #pragma unroll
        for (int ni=0;ni<4;++ni)
          acc[mi][ni] = __builtin_amdgcn_mfma_f32_16x16x32_bf16(av[mi],bv[ni],acc[mi][ni],0,0,0);
    }
    __syncthreads();
  }

  if constexpr (sizeof(TC)==2){
    // ---- bf16 epilogue: bounce tile through LDS, coalesced vector stores ----
    #pragma unroll
    for (int mi=0;mi<4;++mi)
      #pragma unroll
      for (int ni=0;ni<4;++ni)
        #pragma unroll
        for (int r4=0;r4<4;++r4){
          const int row = wr+mi*16+quad*4+r4;
          const int col = wc+ni*16+l15;
          const int g2  = (col>>3) ^ (row&15);        // swizzled 8-col group
          sAB[row*128 + g2*8 + (col&7)] = (__bf16)acc[mi][ni][r4];
        }
    __syncthreads();
    #pragma unroll
    for (int it=0; it<8; ++it){
      const int idx = it*256 + tid;
      const int row = idx>>4, g = idx&15;
      const int g2 = g ^ (row&15);
      bf16x8 v = *(const bf16x8*)&sAB[row*128 + g2*8];
      const int col0 = n0 + g*8;
      if (col0 < Nreal){
        const int grow = m0 + row;
        if (col0 < splitN) *(bf16x8*)&C [(size_t)grow*ldc  + col0]          = v;
        else               *(bf16x8*)&C2[(size_t)grow*ldc2 + (col0-splitN)] = v;
      }
    }
  } else {
    // ---- fp32 epilogue (final head): per-element + bias ----
    #pragma unroll
    for (int ni=0;ni<4;++ni){
      const int col = n0 + wc + ni*16 + l15;
      if (col < Nreal){
        const float badd = bias ? bias[col] : 0.f;
        #pragma unroll
        for (int mi=0;mi<4;++mi){
          #pragma unroll
          for (int r4=0;r4<4;++r4){
            const int row = m0 + wr + mi*16 + quad*4 + r4;
            C[(size_t)row*ldc + col] = (TC)(acc[mi][ni][r4] + badd);
          }
        }
      }
    }
  }
}

// ---------------------------------------------------------------------------
// merged fp32->bf16 casts: 4 (src,dst) regions, one launch. n* in float4 units.
// ---------------------------------------------------------------------------
__global__ __launch_bounds__(256) void cast4_k(
    const float* __restrict__ s0, __bf16* __restrict__ d0, int n0,
    const float* __restrict__ s1, __bf16* __restrict__ d1, int n1,
    const float* __restrict__ s2, __bf16* __restrict__ d2, int n2,
    const float* __restrict__ s3, __bf16* __restrict__ d3, int n3)
{
  int i = blockIdx.x*256 + threadIdx.x;
  const float* s; __bf16* d;
  if (i < n0){ s=s0; d=d0; }
  else if ((i-=n0) < n1){ s=s1; d=d1; }
  else if ((i-=n1) < n2){ s=s2; d=d2; }
  else if ((i-=n2) < n3){ s=s3; d=d3; }
  else return;
  float4 v = ((const float4*)s)[i];
  bf16x4 o;
  o[0]=(__bf16)v.x; o[1]=(__bf16)v.y; o[2]=(__bf16)v.z; o[3]=(__bf16)v.w;
  ((bf16x4*)d)[i] = o;
}

// ---------------------------------------------------------------------------
// Causal depthwise conv (width 4) + bias + SiLU, 8 channels per thread.
// ---------------------------------------------------------------------------
__global__ __launch_bounds__(256) void conv_silu_k(
    const __bf16* __restrict__ xbw, const float* __restrict__ cw,
    const float* __restrict__ cb, __bf16* __restrict__ xout,
    __bf16* __restrict__ bcout)
{
  int idx = blockIdx.x*256 + threadIdx.x;
  if (idx >= BATCH*SEQ*CSEG) return;
  const int seg = idx % CSEG;
  const int bt  = idx / CSEG;
  const int t = bt % SEQ, b = bt / SEQ;
  const int d0 = seg*8;
  const __bf16* src = xbw + ((size_t)b*SEQ + t)*XBW + d0;
  bf16x8 z8;
  #pragma unroll
  for (int e=0;e<8;++e) z8[e]=(__bf16)0.f;
  bf16x8 x3 = *(const bf16x8*)src;
  bf16x8 x2 = (t>=1)? *(const bf16x8*)(src -   XBW) : z8;
  bf16x8 x1 = (t>=2)? *(const bf16x8*)(src - 2*XBW) : z8;
  bf16x8 x0 = (t>=3)? *(const bf16x8*)(src - 3*XBW) : z8;
  const float4* w4  = (const float4*)(cw + (size_t)d0*4);
  const float4* cb4 = (const float4*)(cb + d0);
  float4 cbl = cb4[0], cbh = cb4[1];
  bf16x8 o;
  #pragma unroll
  for (int e=0;e<8;++e){
    float4 w = w4[e];
    float acc = (e<4 ? (&cbl.x)[e] : (&cbh.x)[e-4])
              + w.x*(float)x0[e] + w.y*(float)x1[e]
              + w.z*(float)x2[e] + w.w*(float)x3[e];
    o[e] = (__bf16)siluf_(acc);
  }
  if (d0 < DI) *(bf16x8*)(xout  + ((size_t)b*SEQ+t)*DI  + d0)       = o;
  else         *(bf16x8*)(bcout + ((size_t)b*SEQ+t)*128 + (d0-DI))  = o;
}

// ---------------------------------------------------------------------------
// Fused SSD: one block per (b,h). (unchanged from R7 — see comments there)
// ---------------------------------------------------------------------------
__global__ __launch_bounds__(256) void ssd_fused_k(
    const __bf16* __restrict__ bc,
    __bf16* __restrict__ xy,
    const __bf16* __restrict__ xbw,
    const float* __restrict__ dtb_, const float* __restrict__ alog_,
    const float* __restrict__ dp_)
{
  __shared__ __bf16 sB[64*72], sC[64*72], sXT[64*72], sBwT[64*72],
                    sS[64*72], sHT[64*72];
  __shared__ float sCS[SEQ], sDT[SEQ];
  const int bid = blockIdx.x;
  const int h = bid & 15, b = bid >> 4;
  const int tid = threadIdx.x, wave = tid>>6, lane = tid&63;
  const int l15 = lane&15, quad = lane>>4;
  const int wm = (wave>>1)*32, wn = (wave&1)*32;

  const float Ah  = -__expf(alog_[h]);
  const float dtb = dtb_[h];
  const float Dh  = dp_[h];

  for (int t = tid; t < SEQ; t += 256){
    float raw = (float)xbw[((size_t)b*SEQ + t)*XBW + CDIM + h];
    float dt = softplusf_(raw + dtb);
    sDT[t] = dt;
    sCS[t] = dt*Ah;
  }
  __syncthreads();
  for (int ch = wave; ch < NC; ch += 4){
    float s = sCS[ch*64 + lane];
    #pragma unroll
    for (int off=1; off<64; off<<=1){
      float v = __shfl_up(s, off);
      if (lane >= off) s += v;
    }
    sCS[ch*64 + lane] = s;
  }
  __syncthreads();

  f32x4 run[2][2];
  #pragma unroll
  for (int a=0;a<2;++a)
    #pragma unroll
    for (int d=0;d<2;++d) run[a][d] = (f32x4){0,0,0,0};

  for (int c = 0; c < NC; ++c){
    const int t0 = c*64;
    {
      const int r = tid>>2, seg = (tid&3)*16;
      const __bf16* row = bc + ((size_t)b*SEQ + t0 + r)*128;
      bf16x8 vb0 = *(const bf16x8*)(row + seg);
      bf16x8 vb1 = *(const bf16x8*)(row + seg + 8);
      bf16x8 vc0 = *(const bf16x8*)(row + 64 + seg);
      bf16x8 vc1 = *(const bf16x8*)(row + 64 + seg + 8);
      *(bf16x8*)&sB[r*72+seg]   = vb0;
      *(bf16x8*)&sB[r*72+seg+8] = vb1;
      *(bf16x8*)&sC[r*72+seg]   = vc0;
      *(bf16x8*)&sC[r*72+seg+8] = vc1;
      const float w = __expf(sCS[t0+63] - sCS[t0+r]) * sDT[t0+r];  // <=0 exp
      #pragma unroll
      for (int e=0;e<8;++e){
        sBwT[(seg+e)*72 + r]   = (__bf16)(w*(float)vb0[e]);
        sBwT[(seg+8+e)*72 + r] = (__bf16)(w*(float)vb1[e]);
      }
      const __bf16* xrow = xy + ((size_t)b*SEQ + t0 + r)*DI + h*64;
      bf16x8 vx0 = *(const bf16x8*)(xrow + seg);
      bf16x8 vx1 = *(const bf16x8*)(xrow + seg + 8);
      #pragma unroll
      for (int e=0;e<8;++e){
        sXT[(seg+e)*72 + r]   = vx0[e];
        sXT[(seg+8+e)*72 + r] = vx1[e];
      }
    }
    __syncthreads();

    f32x4 aS[2][2];
    #pragma unroll
    for (int a=0;a<2;++a)
      #pragma unroll
      for (int d=0;d<2;++d) aS[a][d] = (f32x4){0,0,0,0};
    #pragma unroll
    for (int kk=0; kk<64; kk+=32){
      const int kf = kk + quad*8;
      bf16x8 a0 = *(const bf16x8*)&sC[(wm+l15)*72+kf];
      bf16x8 a1 = *(const bf16x8*)&sC[(wm+16+l15)*72+kf];
      bf16x8 b0 = *(const bf16x8*)&sB[(wn+l15)*72+kf];
      bf16x8 b1 = *(const bf16x8*)&sB[(wn+16+l15)*72+kf];
      aS[0][0] = __builtin_amdgcn_mfma_f32_16x16x32_bf16(a0,b0,aS[0][0],0,0,0);
      aS[0][1] = __builtin_amdgcn_mfma_f32_16x16x32_bf16(a0,b1,aS[0][1],0,0,0);
      aS[1][0] = __builtin_amdgcn_mfma_f32_16x16x32_bf16(a1,b0,aS[1][0],0,0,0);
      aS[1][1] = __builtin_amdgcn_mfma_f32_16x16x32_bf16(a1,b1,aS[1][1],0,0,0);
    }
    #pragma unroll
    for (int mi=0;mi<2;++mi)
      #pragma unroll
      for (int ni=0;ni<2;++ni)
        #pragma unroll
        for (int r4=0;r4<4;++r4){
          const int i = wm+mi*16+quad*4+r4, j = wn+ni*16+l15;
          float ed = __expf(fminf(sCS[t0+i]-sCS[t0+j], 0.f)) * sDT[t0+j];
          float v = aS[mi][ni][r4]*ed;
          sS[i*72+j] = (__bf16)((j<=i)? v : 0.f);
          sHT[j*72+i] = (__bf16)run[mi][ni][r4];   // [p][n]
        }
    __syncthreads();

    f32x4 aY[2][2], aH[2][2], aYi[2][2];
    #pragma unroll
    for (int a=0;a<2;++a)
      #pragma unroll
      for (int d=0;d<2;++d){
        aY[a][d]=(f32x4){0,0,0,0}; aH[a][d]=(f32x4){0,0,0,0};
        aYi[a][d]=(f32x4){0,0,0,0};
      }
    #pragma unroll
    for (int kk=0; kk<64; kk+=32){
      const int kf = kk + quad*8;
      bf16x8 b0 = *(const bf16x8*)&sXT[(wn+l15)*72+kf];
      bf16x8 b1 = *(const bf16x8*)&sXT[(wn+16+l15)*72+kf];
      bf16x8 s0 = *(const bf16x8*)&sS[(wm+l15)*72+kf];
      bf16x8 s1 = *(const bf16x8*)&sS[(wm+16+l15)*72+kf];
      bf16x8 w0 = *(const bf16x8*)&sBwT[(wm+l15)*72+kf];
      bf16x8 w1 = *(const bf16x8*)&sBwT[(wm+16+l15)*72+kf];
      bf16x8 c0 = *(const bf16x8*)&sC[(wm+l15)*72+kf];
      bf16x8 c1 = *(const bf16x8*)&sC[(wm+16+l15)*72+kf];
      bf16x8 h0 = *(const bf16x8*)&sHT[(wn+l15)*72+kf];
      bf16x8 h1 = *(const bf16x8*)&sHT[(wn+16+l15)*72+kf];
      aY[0][0] = __builtin_amdgcn_mfma_f32_16x16x32_bf16(s0,b0,aY[0][0],0,0,0);
      aY[0][1] = __builtin_amdgcn_mfma_f32_16x16x32_bf16(s0,b1,aY[0][1],0,0,0);
      aY[1][0] = __builtin_amdgcn_mfma_f32_16x16x32_bf16(s1,b0,aY[1][0],0,0,0);
      aY[1][1] = __builtin_amdgcn_mfma_f32_16x16x32_bf16(s1,b1,aY[1][1],0,0,0);
      aH[0][0] = __builtin_amdgcn_mfma_f32_16x16x32_bf16(w0,b0,aH[0][0],0,0,0);
      aH[0][1] = __builtin_amdgcn_mfma_f32_16x16x32_bf16(w0,b1,aH[0][1],0,0,0);
      aH[1][0] = __builtin_amdgcn_mfma_f32_16x16x32_bf16(w1,b0,aH[1][0],0,0,0);
      aH[1][1] = __builtin_amdgcn_mfma_f32_16x16x32_bf16(w1,b1,aH[1][1],0,0,0);
      aYi[0][0] = __builtin_amdgcn_mfma_f32_16x16x32_bf16(c0,h0,aYi[0][0],0,0,0);
      aYi[0][1] = __builtin_amdgcn_mfma_f32_16x16x32_bf16(c0,h1,aYi[0][1],0,0,0);
      aYi[1][0] = __builtin_amdgcn_mfma_f32_16x16x32_bf16(c1,h0,aYi[1][0],0,0,0);
      aYi[1][1] = __builtin_amdgcn_mfma_f32_16x16x32_bf16(c1,h1,aYi[1][1],0,0,0);
    }

    const float lam = __expf(sCS[t0+63]);
    #pragma unroll
    for (int mi=0;mi<2;++mi)
      #pragma unroll
      for (int ni=0;ni<2;++ni)
        #pragma unroll
        for (int r4=0;r4<4;++r4){
          const int i = wm+mi*16+quad*4+r4;
          const int p = wn+ni*16+l15;
          const float xval = (float)sXT[p*72 + i];
          const float e2 = __expf(sCS[t0+i]);    // <=1 (cs<=0)
          const float yv = aY[mi][ni][r4] + Dh*xval + e2*aYi[mi][ni][r4];
          xy[((size_t)b*SEQ + t0 + i)*DI + h*64 + p] = (__bf16)yv;
          run[mi][ni][r4] = run[mi][ni][r4]*lam + aH[mi][ni][r4];
        }
    __syncthreads();
  }
}

// ---------------------------------------------------------------------------
__global__ __launch_bounds__(256) void gate_rms_k(
    __bf16* __restrict__ y, const __bf16* __restrict__ z, const float* __restrict__ nw)
{
  __shared__ float red[4];
  const int tid = threadIdx.x;
  const int sub = tid>>7;
  const int off = (tid&127)*8;
  const size_t row = (size_t)blockIdx.x*2 + sub;
  __bf16* yrow = y + row*DI;
  const __bf16* zrow = z + row*DI;
  bf16x8 yv = *(const bf16x8*)(yrow+off);
  bf16x8 zv = *(const bf16x8*)(zrow+off);
  float u[8]; float ss = 0.f;
  #pragma unroll
  for (int e=0;e<8;++e){
    float uu = (float)yv[e]*siluf_((float)zv[e]);
    u[e]=uu; ss += uu*uu;
  }
  #pragma unroll
  for (int o=32;o;o>>=1) ss += __shfl_xor(ss,o);
  if ((tid&63)==0) red[tid>>6] = ss;
  __syncthreads();
  ss = red[sub*2] + red[sub*2+1];
  const float sc = rsqrtf(ss*(1.f/DI) + EPSF);
  const float4* nw4 = (const float4*)(nw + off);
  float4 n0 = nw4[0], n1 = nw4[1];
  bf16x8 o;
  #pragma unroll
  for (int e=0;e<8;++e)
    o[e] = (__bf16)(u[e]*sc*(e<4 ? (&n0.x)[e] : (&n1.x)[e-4]));
  *(bf16x8*)(yrow+off) = o;
}

// ---------------------------------------------------------------------------
__global__ __launch_bounds__(256) void add_ln_k(
    const __bf16* __restrict__ tmp, __bf16* __restrict__ resio,
    const float* __restrict__ w, const float* __restrict__ bb)
{
  const int tid = threadIdx.x, lane = tid&63;
  const size_t row = (size_t)blockIdx.x*4 + (tid>>6);
  const int off = lane*8;
  const __bf16* trow = tmp + row*DM;
  __bf16* rrow = resio + row*DM;
  bf16x8 tv = *(const bf16x8*)(trow+off);
  bf16x8 rv = *(const bf16x8*)(rrow+off);
  float v[8]; float s = 0.f;
  #pragma unroll
  for (int e=0;e<8;++e){ v[e]=(float)tv[e]+(float)rv[e]; s += v[e]; }
  #pragma unroll
  for (int o=32;o;o>>=1) s += __shfl_xor(s,o);
  const float mean = s*(1.f/DM);
  float q = 0.f;
  #pragma unroll
  for (int e=0;e<8;++e){ v[e]-=mean; q += v[e]*v[e]; }
  #pragma unroll
  for (int o=32;o;o>>=1) q += __shfl_xor(q,o);
  const float rstd = rsqrtf(q*(1.f/DM) + EPSF);
  const float4* w4 = (const float4*)(w + off);
  const float4* b4 = (const float4*)(bb + off);
  float4 w0=w4[0], w1=w4[1], b0=b4[0], b1=b4[1];
  bf16x8 o8;
  #pragma unroll
  for (int e=0;e<8;++e){
    float we = e<4 ? (&w0.x)[e] : (&w1.x)[e-4];
    float be = e<4 ? (&b0.x)[e] : (&b1.x)[e-4];
    o8[e] = (__bf16)(v[e]*rstd*we + be);
  }
  *(bf16x8*)(rrow+off) = o8;
}

// ---------------------------------------------------------------------------
extern "C" void kernel_launch(void* const* d_in, const int* in_sizes, int n_in,
                              void* d_out, int out_size, void* d_ws, size_t ws_size,
                              hipStream_t stream)
{
  const float* x         = (const float*)d_in[0];
  const float* in_proj_w = (const float*)d_in[1];
  const float* conv_w    = (const float*)d_in[2];
  const float* conv_b    = (const float*)d_in[3];
  const float* dt_bias   = (const float*)d_in[4];
  const float* A_log     = (const float*)d_in[5];
  const float* Dp        = (const float*)d_in[6];
  const float* norm_w    = (const float*)d_in[7];
  const float* out_proj_w= (const float*)d_in[8];
  const float* ln_w      = (const float*)d_in[9];
  const float* ln_b      = (const float*)d_in[10];
  const float* final_w   = (const float*)d_in[11];
  const float* final_b   = (const float*)d_in[12];
  float* out = (float*)d_out;

  const size_t ROWS = (size_t)BATCH*SEQ;        // 16384
  __bf16* wbf_in  = (__bf16*)d_ws;
  __bf16* wbf_out = wbf_in  + (size_t)NL*DPROJ*DM;
  __bf16* wbf_fin = wbf_out + (size_t)NL*DM*DI;
  __bf16* zbuf    = wbf_fin + (size_t)DM*DM;
  __bf16* xbw     = zbuf    + ROWS*DI;
  __bf16* ybuf    = xbw     + ROWS*XBW;
  __bf16* bcb     = ybuf    + ROWS*DI;
  __bf16* xcur    = bcb     + ROWS*128;
  __bf16* tmp  = xbw;     // alias: xbw dead after ssd_fused reads dt

  {
    int n1 = NL*DPROJ*DM/4, n2 = NL*DM*DI/4, n3 = DM*DM/4, n4 = (int)(ROWS*DM/4);
    int tot = n1+n2+n3+n4;
    cast4_k<<<(tot+255)/256, 256, 0, stream>>>(
        in_proj_w, wbf_in, n1, out_proj_w, wbf_out, n2,
        final_w, wbf_fin, n3, x, xcur, n4);
  }

  const int convTotal = BATCH*SEQ*CSEG;
  const int BIGN = 1<<30;

  for (int l=0; l<NL; ++l){
    const __bf16* wl = wbf_in + (size_t)l*DPROJ*DM;
    // in_proj, single launch: cols 0..1024 -> zbuf, 1024..2192 -> xbw
    gemm128<__bf16><<<dim3((DPROJ+127)/128, (int)(ROWS/128)), 256, 0, stream>>>(
        xcur, wl, zbuf, xbw, nullptr, (int)ROWS, DPROJ, DI, XBW, DI, DM, 0);
    conv_silu_k<<<(convTotal+255)/256, 256, 0, stream>>>(
        xbw, conv_w + (size_t)l*CDIM*4, conv_b + (size_t)l*CDIM, ybuf, bcb);
    ssd_fused_k<<<BATCH*NH, 256, 0, stream>>>(
        bcb, ybuf, xbw, dt_bias + l*NH, A_log + l*NH, Dp + l*NH);
    gate_rms_k<<<(int)(ROWS/2), 256, 0, stream>>>(ybuf, zbuf, norm_w + (size_t)l*DI);
    gemm128<__bf16><<<dim3(DM/128, (int)(ROWS/128)), 256, 0, stream>>>(
        ybuf, wbf_out + (size_t)l*DM*DI, tmp, tmp, nullptr, (int)ROWS, DM, DM, DM, BIGN, DI, 0);
    add_ln_k<<<(int)(ROWS/4), 256, 0, stream>>>(tmp, xcur, ln_w + l*DM, ln_b + l*DM);
  }
  // final head: A-rows remapped to the last PREDN timesteps of xcur (gather fused)
  gemm128<float><<<dim3(DM/128, (BATCH*PREDN)/128), 256, 0, stream>>>(
      xcur, wbf_fin, out, out, final_b, BATCH*PREDN, DM, DM, DM, BIGN, DM, 1);
}

// Round 9
// 835.475 us; speedup vs baseline: 4.1463x; 1.0366x over previous
//
#include <hip/hip_runtime.h>
#include <stdint.h>

#define BATCH 32
#define SEQ   512
#define DM    512
#define NL    4
#define DSTATE 64
#define DI    1024   // D_INNER
#define NH    16
#define HD    64
#define PREDN 96
#define CDIM  1152   // DI + 2*DSTATE
#define CSEG  144    // CDIM/8
#define DPROJ 2192
#define XBW   1168   // xBC (1152) + dt (16) columns
#define NC    8      // chunks per sequence
#define EPSF  1e-5f

typedef float  f32x4  __attribute__((ext_vector_type(4)));
typedef __bf16 bf16x4 __attribute__((ext_vector_type(4)));
typedef __bf16 bf16x8 __attribute__((ext_vector_type(8)));

__device__ __forceinline__ float sigmoidf_(float x){ return 1.f/(1.f+__expf(-x)); }
__device__ __forceinline__ float siluf_(float x){ return x*sigmoidf_(x); }
__device__ __forceinline__ float softplusf_(float x){ return (x>20.f)?x:log1pf(__expf(x)); }

// direct global->LDS async copy, 16B per lane
__device__ __forceinline__ void gld16(const void* g, void* l){
  __builtin_amdgcn_global_load_lds((__attribute__((address_space(1))) void*)g,
                                   (__attribute__((address_space(3))) void*)l, 16, 0, 0);
}

// ---------------------------------------------------------------------------
// GEMM (B-transposed): bf16 MFMA, 128x128 tile, BK=64, global_load_lds,
// XOR-swizzled LDS (R6: SQ_LDS_BANK_CONFLICT=0), LDS-bounce bf16 epilogue (R7).
// R8: ROW-TILE IS blockIdx.x (fastest) -> each XCD owns row-tiles = id mod 8,
// per-XCD A footprint 2.1 MB < 4 MB L2 (was: all tiles -> 4x over-fetch).
// Split epilogue: col < splitN -> C (ldc), else -> C2 (ldc2, col-splitN).
// remapA: A-row r reads global row (r/PREDN)*SEQ + (SEQ-PREDN) + r%PREDN.
// ---------------------------------------------------------------------------
template<typename TC>
__global__ __launch_bounds__(256) void gemm128(
    const __bf16* __restrict__ A, const __bf16* __restrict__ W,
    TC* __restrict__ C, TC* __restrict__ C2, const float* __restrict__ bias,
    int M, int Nreal, int ldc, int ldc2, int splitN, int K, int remapA)
{
  __shared__ __bf16 sAB[2*128*64];     // K-loop: sA | sW ; epilogue: 128x128 tile
  __bf16* sA = sAB;
  __bf16* sW = sAB + 128*64;
  const int tid  = threadIdx.x;
  const int m0   = blockIdx.x*128, n0 = blockIdx.y*128;   // row-tile fastest
  const int lane = tid&63, wave = tid>>6;
  const int l15  = lane&15, quad = lane>>4;
  const int wr   = (wave>>1)*64, wc = (wave&1)*64;
  f32x4 acc[4][4];
  #pragma unroll
  for (int a=0;a<4;++a)
    #pragma unroll
    for (int b=0;b<4;++b) acc[a][b] = (f32x4){0,0,0,0};

  for (int k0=0; k0<K; k0+=64){
    #pragma unroll
    for (int j=0;j<4;++j){
      const int f = j*256 + tid;
      const int r = f>>3;
      const int kc = (((f&7) ^ (r&7)))*8;      // XOR-swizzled source col-block
      int ga = m0 + r;
      if (remapA){ int bb = ga/PREDN; ga = bb*SEQ + (SEQ-PREDN) + (ga - bb*PREDN); }
      gld16(A + (size_t)ga*K + k0 + kc, &sA[f*8]);
      int rb = n0 + r; rb = rb < Nreal ? rb : (Nreal-1);
      gld16(W + (size_t)rb*K + k0 + kc, &sW[f*8]);
    }
    __syncthreads();
    #pragma unroll
    for (int kk=0; kk<64; kk+=32){
      const int kcb = (kk>>3) + quad;          // logical col-block 0..7
      bf16x8 av[4], bv[4];
      #pragma unroll
      for (int mi=0;mi<4;++mi){
        const int row = wr+mi*16+l15;
        av[mi] = *(const bf16x8*)&sA[row*64 + ((kcb ^ (row&7))<<3)];
      }
      #pragma unroll
      for (int ni=0;ni<4;++ni){
        const int row = wc+ni*16+l15;
        bv[ni] = *(const bf16x8*)&sW[row*64 + ((kcb ^ (row&7))<<3)];
      }
      #pragma unroll
      for (int mi=0;mi<4;++mi)
        #pragma unroll
        for (int ni=0;ni<4;++ni)
          acc[mi][ni] = __builtin_amdgcn_mfma_f32_16x16x32_bf16(av[mi],bv[ni],acc[mi][ni],0,0,0);
    }
    __syncthreads();
  }

  if constexpr (sizeof(TC)==2){
    // ---- bf16 epilogue: bounce tile through LDS, coalesced vector stores ----
    #pragma unroll
    for (int mi=0;mi<4;++mi)
      #pragma unroll
      for (int ni=0;ni<4;++ni)
        #pragma unroll
        for (int r4=0;r4<4;++r4){
          const int row = wr+mi*16+quad*4+r4;
          const int col = wc+ni*16+l15;
          const int g2  = (col>>3) ^ (row&15);        // swizzled 8-col group
          sAB[row*128 + g2*8 + (col&7)] = (__bf16)acc[mi][ni][r4];
        }
    __syncthreads();
    #pragma unroll
    for (int it=0; it<8; ++it){
      const int idx = it*256 + tid;
      const int row = idx>>4, g = idx&15;
      const int g2 = g ^ (row&15);
      bf16x8 v = *(const bf16x8*)&sAB[row*128 + g2*8];
      const int col0 = n0 + g*8;
      if (col0 < Nreal){
        const int grow = m0 + row;
        if (col0 < splitN) *(bf16x8*)&C [(size_t)grow*ldc  + col0]          = v;
        else               *(bf16x8*)&C2[(size_t)grow*ldc2 + (col0-splitN)] = v;
      }
    }
  } else {
    // ---- fp32 epilogue (final head): per-element + bias ----
    #pragma unroll
    for (int ni=0;ni<4;++ni){
      const int col = n0 + wc + ni*16 + l15;
      if (col < Nreal){
        const float badd = bias ? bias[col] : 0.f;
        #pragma unroll
        for (int mi=0;mi<4;++mi){
          #pragma unroll
          for (int r4=0;r4<4;++r4){
            const int row = m0 + wr + mi*16 + quad*4 + r4;
            C[(size_t)row*ldc + col] = (TC)(acc[mi][ni][r4] + badd);
          }
        }
      }
    }
  }
}

// ---------------------------------------------------------------------------
// merged fp32->bf16 casts: 4 (src,dst) regions, one launch. n* in float4 units.
// ---------------------------------------------------------------------------
__global__ __launch_bounds__(256) void cast4_k(
    const float* __restrict__ s0, __bf16* __restrict__ d0, int n0,
    const float* __restrict__ s1, __bf16* __restrict__ d1, int n1,
    const float* __restrict__ s2, __bf16* __restrict__ d2, int n2,
    const float* __restrict__ s3, __bf16* __restrict__ d3, int n3)
{
  int i = blockIdx.x*256 + threadIdx.x;
  const float* s; __bf16* d;
  if (i < n0){ s=s0; d=d0; }
  else if ((i-=n0) < n1){ s=s1; d=d1; }
  else if ((i-=n1) < n2){ s=s2; d=d2; }
  else if ((i-=n2) < n3){ s=s3; d=d3; }
  else return;
  float4 v = ((const float4*)s)[i];
  bf16x4 o;
  o[0]=(__bf16)v.x; o[1]=(__bf16)v.y; o[2]=(__bf16)v.z; o[3]=(__bf16)v.w;
  ((bf16x4*)d)[i] = o;
}

// ---------------------------------------------------------------------------
// Causal depthwise conv (width 4) + bias + SiLU, 8 channels per thread.
// ---------------------------------------------------------------------------
__global__ __launch_bounds__(256) void conv_silu_k(
    const __bf16* __restrict__ xbw, const float* __restrict__ cw,
    const float* __restrict__ cb, __bf16* __restrict__ xout,
    __bf16* __restrict__ bcout)
{
  int idx = blockIdx.x*256 + threadIdx.x;
  if (idx >= BATCH*SEQ*CSEG) return;
  const int seg = idx % CSEG;
  const int bt  = idx / CSEG;
  const int t = bt % SEQ, b = bt / SEQ;
  const int d0 = seg*8;
  const __bf16* src = xbw + ((size_t)b*SEQ + t)*XBW + d0;
  bf16x8 z8;
  #pragma unroll
  for (int e=0;e<8;++e) z8[e]=(__bf16)0.f;
  bf16x8 x3 = *(const bf16x8*)src;
  bf16x8 x2 = (t>=1)? *(const bf16x8*)(src -   XBW) : z8;
  bf16x8 x1 = (t>=2)? *(const bf16x8*)(src - 2*XBW) : z8;
  bf16x8 x0 = (t>=3)? *(const bf16x8*)(src - 3*XBW) : z8;
  const float4* w4  = (const float4*)(cw + (size_t)d0*4);
  const float4* cb4 = (const float4*)(cb + d0);
  float4 cbl = cb4[0], cbh = cb4[1];
  bf16x8 o;
  #pragma unroll
  for (int e=0;e<8;++e){
    float4 w = w4[e];
    float acc = (e<4 ? (&cbl.x)[e] : (&cbh.x)[e-4])
              + w.x*(float)x0[e] + w.y*(float)x1[e]
              + w.z*(float)x2[e] + w.w*(float)x3[e];
    o[e] = (__bf16)siluf_(acc);
  }
  if (d0 < DI) *(bf16x8*)(xout  + ((size_t)b*SEQ+t)*DI  + d0)       = o;
  else         *(bf16x8*)(bcout + ((size_t)b*SEQ+t)*128 + (d0-DI))  = o;
}

// ---------------------------------------------------------------------------
// Fused SSD: one block per (b,h). R8: sS aliases sB (dead after mm1; extra
// barrier between mm1 and mask-write) -> LDS 59.3->50.2 KB -> 3 blocks/CU.
// ---------------------------------------------------------------------------
__global__ __launch_bounds__(256) void ssd_fused_k(
    const __bf16* __restrict__ bc,
    __bf16* __restrict__ xy,
    const __bf16* __restrict__ xbw,
    const float* __restrict__ dtb_, const float* __restrict__ alog_,
    const float* __restrict__ dp_)
{
  __shared__ __bf16 sPool[5*64*72];
  __bf16* sB   = sPool;                // aliased with sS (sB dead after mm1)
  __bf16* sS   = sPool;
  __bf16* sC   = sPool + 1*64*72;
  __bf16* sXT  = sPool + 2*64*72;
  __bf16* sBwT = sPool + 3*64*72;
  __bf16* sHT  = sPool + 4*64*72;
  __shared__ float sCS[SEQ], sDT[SEQ];
  const int bid = blockIdx.x;
  const int h = bid & 15, b = bid >> 4;
  const int tid = threadIdx.x, wave = tid>>6, lane = tid&63;
  const int l15 = lane&15, quad = lane>>4;
  const int wm = (wave>>1)*32, wn = (wave&1)*32;

  const float Ah  = -__expf(alog_[h]);
  const float dtb = dtb_[h];
  const float Dh  = dp_[h];

  for (int t = tid; t < SEQ; t += 256){
    float raw = (float)xbw[((size_t)b*SEQ + t)*XBW + CDIM + h];
    float dt = softplusf_(raw + dtb);
    sDT[t] = dt;
    sCS[t] = dt*Ah;
  }
  __syncthreads();
  for (int ch = wave; ch < NC; ch += 4){
    float s = sCS[ch*64 + lane];
    #pragma unroll
    for (int off=1; off<64; off<<=1){
      float v = __shfl_up(s, off);
      if (lane >= off) s += v;
    }
    sCS[ch*64 + lane] = s;
  }
  __syncthreads();

  f32x4 run[2][2];
  #pragma unroll
  for (int a=0;a<2;++a)
    #pragma unroll
    for (int d=0;d<2;++d) run[a][d] = (f32x4){0,0,0,0};

  for (int c = 0; c < NC; ++c){
    const int t0 = c*64;
    {
      const int r = tid>>2, seg = (tid&3)*16;
      const __bf16* row = bc + ((size_t)b*SEQ + t0 + r)*128;
      bf16x8 vb0 = *(const bf16x8*)(row + seg);
      bf16x8 vb1 = *(const bf16x8*)(row + seg + 8);
      bf16x8 vc0 = *(const bf16x8*)(row + 64 + seg);
      bf16x8 vc1 = *(const bf16x8*)(row + 64 + seg + 8);
      *(bf16x8*)&sB[r*72+seg]   = vb0;
      *(bf16x8*)&sB[r*72+seg+8] = vb1;
      *(bf16x8*)&sC[r*72+seg]   = vc0;
      *(bf16x8*)&sC[r*72+seg+8] = vc1;
      const float w = __expf(sCS[t0+63] - sCS[t0+r]) * sDT[t0+r];  // <=0 exp
      #pragma unroll
      for (int e=0;e<8;++e){
        sBwT[(seg+e)*72 + r]   = (__bf16)(w*(float)vb0[e]);
        sBwT[(seg+8+e)*72 + r] = (__bf16)(w*(float)vb1[e]);
      }
      const __bf16* xrow = xy + ((size_t)b*SEQ + t0 + r)*DI + h*64;
      bf16x8 vx0 = *(const bf16x8*)(xrow + seg);
      bf16x8 vx1 = *(const bf16x8*)(xrow + seg + 8);
      #pragma unroll
      for (int e=0;e<8;++e){
        sXT[(seg+e)*72 + r]   = vx0[e];
        sXT[(seg+8+e)*72 + r] = vx1[e];
      }
    }
    __syncthreads();

    f32x4 aS[2][2];
    #pragma unroll
    for (int a=0;a<2;++a)
      #pragma unroll
      for (int d=0;d<2;++d) aS[a][d] = (f32x4){0,0,0,0};
    #pragma unroll
    for (int kk=0; kk<64; kk+=32){
      const int kf = kk + quad*8;
      bf16x8 a0 = *(const bf16x8*)&sC[(wm+l15)*72+kf];
      bf16x8 a1 = *(const bf16x8*)&sC[(wm+16+l15)*72+kf];
      bf16x8 b0 = *(const bf16x8*)&sB[(wn+l15)*72+kf];
      bf16x8 b1 = *(const bf16x8*)&sB[(wn+16+l15)*72+kf];
      aS[0][0] = __builtin_amdgcn_mfma_f32_16x16x32_bf16(a0,b0,aS[0][0],0,0,0);
      aS[0][1] = __builtin_amdgcn_mfma_f32_16x16x32_bf16(a0,b1,aS[0][1],0,0,0);
      aS[1][0] = __builtin_amdgcn_mfma_f32_16x16x32_bf16(a1,b0,aS[1][0],0,0,0);
      aS[1][1] = __builtin_amdgcn_mfma_f32_16x16x32_bf16(a1,b1,aS[1][1],0,0,0);
    }
    __syncthreads();   // all waves done reading sB before sS(=sB) is written

    #pragma unroll
    for (int mi=0;mi<2;++mi)
      #pragma unroll
      for (int ni=0;ni<2;++ni)
        #pragma unroll
        for (int r4=0;r4<4;++r4){
          const int i = wm+mi*16+quad*4+r4, j = wn+ni*16+l15;
          float ed = __expf(fminf(sCS[t0+i]-sCS[t0+j], 0.f)) * sDT[t0+j];
          float v = aS[mi][ni][r4]*ed;
          sS[i*72+j] = (__bf16)((j<=i)? v : 0.f);
          sHT[j*72+i] = (__bf16)run[mi][ni][r4];   // [p][n]
        }
    __syncthreads();

    f32x4 aY[2][2], aH[2][2], aYi[2][2];
    #pragma unroll
    for (int a=0;a<2;++a)
      #pragma unroll
      for (int d=0;d<2;++d){
        aY[a][d]=(f32x4){0,0,0,0}; aH[a][d]=(f32x4){0,0,0,0};
        aYi[a][d]=(f32x4){0,0,0,0};
      }
    #pragma unroll
    for (int kk=0; kk<64; kk+=32){
      const int kf = kk + quad*8;
      bf16x8 b0 = *(const bf16x8*)&sXT[(wn+l15)*72+kf];
      bf16x8 b1 = *(const bf16x8*)&sXT[(wn+16+l15)*72+kf];
      bf16x8 s0 = *(const bf16x8*)&sS[(wm+l15)*72+kf];
      bf16x8 s1 = *(const bf16x8*)&sS[(wm+16+l15)*72+kf];
      bf16x8 w0 = *(const bf16x8*)&sBwT[(wm+l15)*72+kf];
      bf16x8 w1 = *(const bf16x8*)&sBwT[(wm+16+l15)*72+kf];
      bf16x8 c0 = *(const bf16x8*)&sC[(wm+l15)*72+kf];
      bf16x8 c1 = *(const bf16x8*)&sC[(wm+16+l15)*72+kf];
      bf16x8 h0 = *(const bf16x8*)&sHT[(wn+l15)*72+kf];
      bf16x8 h1 = *(const bf16x8*)&sHT[(wn+16+l15)*72+kf];
      aY[0][0] = __builtin_amdgcn_mfma_f32_16x16x32_bf16(s0,b0,aY[0][0],0,0,0);
      aY[0][1] = __builtin_amdgcn_mfma_f32_16x16x32_bf16(s0,b1,aY[0][1],0,0,0);
      aY[1][0] = __builtin_amdgcn_mfma_f32_16x16x32_bf16(s1,b0,aY[1][0],0,0,0);
      aY[1][1] = __builtin_amdgcn_mfma_f32_16x16x32_bf16(s1,b1,aY[1][1],0,0,0);
      aH[0][0] = __builtin_amdgcn_mfma_f32_16x16x32_bf16(w0,b0,aH[0][0],0,0,0);
      aH[0][1] = __builtin_amdgcn_mfma_f32_16x16x32_bf16(w0,b1,aH[0][1],0,0,0);
      aH[1][0] = __builtin_amdgcn_mfma_f32_16x16x32_bf16(w1,b0,aH[1][0],0,0,0);
      aH[1][1] = __builtin_amdgcn_mfma_f32_16x16x32_bf16(w1,b1,aH[1][1],0,0,0);
      aYi[0][0] = __builtin_amdgcn_mfma_f32_16x16x32_bf16(c0,h0,aYi[0][0],0,0,0);
      aYi[0][1] = __builtin_amdgcn_mfma_f32_16x16x32_bf16(c0,h1,aYi[0][1],0,0,0);
      aYi[1][0] = __builtin_amdgcn_mfma_f32_16x16x32_bf16(c1,h0,aYi[1][0],0,0,0);
      aYi[1][1] = __builtin_amdgcn_mfma_f32_16x16x32_bf16(c1,h1,aYi[1][1],0,0,0);
    }

    const float lam = __expf(sCS[t0+63]);
    #pragma unroll
    for (int mi=0;mi<2;++mi)
      #pragma unroll
      for (int ni=0;ni<2;++ni)
        #pragma unroll
        for (int r4=0;r4<4;++r4){
          const int i = wm+mi*16+quad*4+r4;
          const int p = wn+ni*16+l15;
          const float xval = (float)sXT[p*72 + i];
          const float e2 = __expf(sCS[t0+i]);    // <=1 (cs<=0)
          const float yv = aY[mi][ni][r4] + Dh*xval + e2*aYi[mi][ni][r4];
          xy[((size_t)b*SEQ + t0 + i)*DI + h*64 + p] = (__bf16)yv;
          run[mi][ni][r4] = run[mi][ni][r4]*lam + aH[mi][ni][r4];
        }
    __syncthreads();
  }
}

// ---------------------------------------------------------------------------
__global__ __launch_bounds__(256) void gate_rms_k(
    __bf16* __restrict__ y, const __bf16* __restrict__ z, const float* __restrict__ nw)
{
  __shared__ float red[4];
  const int tid = threadIdx.x;
  const int sub = tid>>7;
  const int off = (tid&127)*8;
  const size_t row = (size_t)blockIdx.x*2 + sub;
  __bf16* yrow = y + row*DI;
  const __bf16* zrow = z + row*DI;
  bf16x8 yv = *(const bf16x8*)(yrow+off);
  bf16x8 zv = *(const bf16x8*)(zrow+off);
  float u[8]; float ss = 0.f;
  #pragma unroll
  for (int e=0;e<8;++e){
    float uu = (float)yv[e]*siluf_((float)zv[e]);
    u[e]=uu; ss += uu*uu;
  }
  #pragma unroll
  for (int o=32;o;o>>=1) ss += __shfl_xor(ss,o);
  if ((tid&63)==0) red[tid>>6] = ss;
  __syncthreads();
  ss = red[sub*2] + red[sub*2+1];
  const float sc = rsqrtf(ss*(1.f/DI) + EPSF);
  const float4* nw4 = (const float4*)(nw + off);
  float4 n0 = nw4[0], n1 = nw4[1];
  bf16x8 o;
  #pragma unroll
  for (int e=0;e<8;++e)
    o[e] = (__bf16)(u[e]*sc*(e<4 ? (&n0.x)[e] : (&n1.x)[e-4]));
  *(bf16x8*)(yrow+off) = o;
}

// ---------------------------------------------------------------------------
__global__ __launch_bounds__(256) void add_ln_k(
    const __bf16* __restrict__ tmp, __bf16* __restrict__ resio,
    const float* __restrict__ w, const float* __restrict__ bb)
{
  const int tid = threadIdx.x, lane = tid&63;
  const size_t row = (size_t)blockIdx.x*4 + (tid>>6);
  const int off = lane*8;
  const __bf16* trow = tmp + row*DM;
  __bf16* rrow = resio + row*DM;
  bf16x8 tv = *(const bf16x8*)(trow+off);
  bf16x8 rv = *(const bf16x8*)(rrow+off);
  float v[8]; float s = 0.f;
  #pragma unroll
  for (int e=0;e<8;++e){ v[e]=(float)tv[e]+(float)rv[e]; s += v[e]; }
  #pragma unroll
  for (int o=32;o;o>>=1) s += __shfl_xor(s,o);
  const float mean = s*(1.f/DM);
  float q = 0.f;
  #pragma unroll
  for (int e=0;e<8;++e){ v[e]-=mean; q += v[e]*v[e]; }
  #pragma unroll
  for (int o=32;o;o>>=1) q += __shfl_xor(q,o);
  const float rstd = rsqrtf(q*(1.f/DM) + EPSF);
  const float4* w4 = (const float4*)(w + off);
  const float4* b4 = (const float4*)(bb + off);
  float4 w0=w4[0], w1=w4[1], b0=b4[0], b1=b4[1];
  bf16x8 o8;
  #pragma unroll
  for (int e=0;e<8;++e){
    float we = e<4 ? (&w0.x)[e] : (&w1.x)[e-4];
    float be = e<4 ? (&b0.x)[e] : (&b1.x)[e-4];
    o8[e] = (__bf16)(v[e]*rstd*we + be);
  }
  *(bf16x8*)(rrow+off) = o8;
}

// ---------------------------------------------------------------------------
extern "C" void kernel_launch(void* const* d_in, const int* in_sizes, int n_in,
                              void* d_out, int out_size, void* d_ws, size_t ws_size,
                              hipStream_t stream)
{
  const float* x         = (const float*)d_in[0];
  const float* in_proj_w = (const float*)d_in[1];
  const float* conv_w    = (const float*)d_in[2];
  const float* conv_b    = (const float*)d_in[3];
  const float* dt_bias   = (const float*)d_in[4];
  const float* A_log     = (const float*)d_in[5];
  const float* Dp        = (const float*)d_in[6];
  const float* norm_w    = (const float*)d_in[7];
  const float* out_proj_w= (const float*)d_in[8];
  const float* ln_w      = (const float*)d_in[9];
  const float* ln_b      = (const float*)d_in[10];
  const float* final_w   = (const float*)d_in[11];
  const float* final_b   = (const float*)d_in[12];
  float* out = (float*)d_out;

  const size_t ROWS = (size_t)BATCH*SEQ;        // 16384
  __bf16* wbf_in  = (__bf16*)d_ws;
  __bf16* wbf_out = wbf_in  + (size_t)NL*DPROJ*DM;
  __bf16* wbf_fin = wbf_out + (size_t)NL*DM*DI;
  __bf16* zbuf    = wbf_fin + (size_t)DM*DM;
  __bf16* xbw     = zbuf    + ROWS*DI;
  __bf16* ybuf    = xbw     + ROWS*XBW;
  __bf16* bcb     = ybuf    + ROWS*DI;
  __bf16* xcur    = bcb     + ROWS*128;
  __bf16* tmp  = xbw;     // alias: xbw dead after ssd_fused reads dt

  {
    int n1 = NL*DPROJ*DM/4, n2 = NL*DM*DI/4, n3 = DM*DM/4, n4 = (int)(ROWS*DM/4);
    int tot = n1+n2+n3+n4;
    cast4_k<<<(tot+255)/256, 256, 0, stream>>>(
        in_proj_w, wbf_in, n1, out_proj_w, wbf_out, n2,
        final_w, wbf_fin, n3, x, xcur, n4);
  }

  const int convTotal = BATCH*SEQ*CSEG;
  const int BIGN = 1<<30;

  for (int l=0; l<NL; ++l){
    const __bf16* wl = wbf_in + (size_t)l*DPROJ*DM;
    // in_proj: grid x = row-tile (XCD A-locality), y = col-tile
    gemm128<__bf16><<<dim3((int)(ROWS/128), (DPROJ+127)/128), 256, 0, stream>>>(
        xcur, wl, zbuf, xbw, nullptr, (int)ROWS, DPROJ, DI, XBW, DI, DM, 0);
    conv_silu_k<<<(convTotal+255)/256, 256, 0, stream>>>(
        xbw, conv_w + (size_t)l*CDIM*4, conv_b + (size_t)l*CDIM, ybuf, bcb);
    ssd_fused_k<<<BATCH*NH, 256, 0, stream>>>(
        bcb, ybuf, xbw, dt_bias + l*NH, A_log + l*NH, Dp + l*NH);
    gate_rms_k<<<(int)(ROWS/2), 256, 0, stream>>>(ybuf, zbuf, norm_w + (size_t)l*DI);
    gemm128<__bf16><<<dim3((int)(ROWS/128), DM/128), 256, 0, stream>>>(
        ybuf, wbf_out + (size_t)l*DM*DI, tmp, tmp, nullptr, (int)ROWS, DM, DM, DM, BIGN, DI, 0);
    add_ln_k<<<(int)(ROWS/4), 256, 0, stream>>>(tmp, xcur, ln_w + l*DM, ln_b + l*DM);
  }
  // final head: A-rows remapped to the last PREDN timesteps of xcur
  gemm128<float><<<dim3((BATCH*PREDN)/128, DM/128), 256, 0, stream>>>(
      xcur, wbf_fin, out, out, final_b, BATCH*PREDN, DM, DM, DM, BIGN, DM, 1);
}